// Round 7
// baseline (1249.398 us; speedup 1.0000x reference)
//
#include <hip/hip_runtime.h>
#include <hip/hip_bf16.h>

#define N_NODES  20000
#define N_EDGES  160000
#define N_TOT_E  180000   // edges + self loops
#define N_GRAPHS 64
#define EMBED_DIM 32
#define IN_GNN   36
#define K1PAD    64       // gemm1 K padded for MFMA
#define H1       2048
#define H2       1024
#define CHUNK0   10112    // 79 * 128; chunk1 = 9888 = N_NODES - CHUNK0

typedef unsigned short u16;
typedef short bf16x8 __attribute__((ext_vector_type(8)));
typedef float f32x4  __attribute__((ext_vector_type(4)));

__device__ inline u16 f32_to_bf16(float f) {
    union { float f; unsigned u; } v; v.f = f;
    unsigned lsb = (v.u >> 16) & 1u;
    return (u16)((v.u + 0x7fffu + lsb) >> 16);
}
__device__ inline float bf16_to_f32(u16 h) {
    union { unsigned u; float f; } v; v.u = ((unsigned)h) << 16;
    return v.f;
}

// ---------------- small utility kernels ----------------

__global__ void fill_i32(int* p, int v, int n) {
    int i = blockIdx.x * 256 + threadIdx.x;
    if (i < n) p[i] = v;
}

__global__ void deg_accum(const int* __restrict__ ei, int* indeg) {
    int e = blockIdx.x * 256 + threadIdx.x;
    if (e < N_EDGES) atomicAdd(&indeg[ei[N_EDGES + e]], 1);
}

__global__ void deg_to_dinv(const int* __restrict__ indeg, float* __restrict__ d) {
    int i = blockIdx.x * 256 + threadIdx.x;
    if (i < N_NODES) d[i] = rsqrtf((float)indeg[i]);   // deg >= 1 (self loop)
}

__global__ void build_xfeat(const int* __restrict__ ids, const float* __restrict__ other,
                            const float* __restrict__ emb, float* __restrict__ xf) {
    int idx = blockIdx.x * 256 + threadIdx.x;   // node*36 + d
    if (idx >= N_NODES * IN_GNN) return;
    int i = idx / IN_GNN;
    int d = idx - i * IN_GNN;
    float v = (d < EMBED_DIM) ? emb[(size_t)ids[i] * EMBED_DIM + d]
                              : other[i * 4 + (d - EMBED_DIM)];
    xf[idx] = v;
}

// ---------------- CSR build: fast single-block scan via wave shuffles ------------
__global__ __launch_bounds__(1024) void scan_offsets(const int* __restrict__ indeg,
                                                     int* __restrict__ off,
                                                     int* __restrict__ cursor) {
    __shared__ int wsum[16];
    int tid = threadIdx.x;
    int lane = tid & 63, wid = tid >> 6;
    int base = 0;
    for (int start = 0; start < N_NODES; start += 1024) {
        int i = start + tid;
        int v = (i < N_NODES) ? indeg[i] : 0;
        // 64-lane inclusive scan
        int x = v;
#pragma unroll
        for (int d = 1; d < 64; d <<= 1) {
            int y = __shfl_up(x, d);
            if (lane >= d) x += y;
        }
        if (lane == 63) wsum[wid] = x;
        __syncthreads();
        if (wid == 0 && lane < 16) {
            int w = wsum[lane];
#pragma unroll
            for (int d = 1; d < 16; d <<= 1) {
                int y = __shfl_up(w, d, 16);
                if ((lane & 15) >= d) w += y;
            }
            wsum[lane] = w;
        }
        __syncthreads();
        int incl = x + (wid > 0 ? wsum[wid - 1] : 0);
        int excl = base + incl - v;
        if (i < N_NODES) { off[i] = excl; cursor[i] = excl; }
        int total = wsum[15];
        __syncthreads();   // protect wsum before next iteration overwrites
        base += total;
    }
    if (tid == 0) off[N_NODES] = N_TOT_E;
}

__global__ void csr_fill(const int* __restrict__ ei, const float* __restrict__ dinv,
                         int* __restrict__ cursor,
                         int* __restrict__ csr_src, float* __restrict__ csr_nrm) {
    int e = blockIdx.x * 256 + threadIdx.x;
    if (e >= N_TOT_E) return;
    int s, t;
    if (e < N_EDGES) { s = ei[e]; t = ei[N_EDGES + e]; }
    else             { s = t = e - N_EDGES; }
    int pos = atomicAdd(&cursor[t], 1);
    csr_src[pos] = s;
    csr_nrm[pos] = dinv[s] * dinv[t];
}

// ---------------- layer-1 aggregation via CSR gather -> hi/lo bf16, [node][64] padded
__global__ void agg_csr_36(const int* __restrict__ off, const int* __restrict__ csr_src,
                           const float* __restrict__ csr_nrm,
                           const float* __restrict__ xf,
                           u16* __restrict__ aggh, u16* __restrict__ aggl) {
    int idx = blockIdx.x * 256 + threadIdx.x;   // node*64 + d
    if (idx >= N_NODES * K1PAD) return;
    int node = idx >> 6;
    int d = idx & 63;
    u16 hi = 0, lo = 0;
    if (d < IN_GNN) {
        int p0 = off[node], p1 = off[node + 1];
        float acc = 0.0f;
        for (int p = p0; p < p1; p++)
            acc += xf[csr_src[p] * IN_GNN + d] * csr_nrm[p];
        hi = f32_to_bf16(acc);
        lo = f32_to_bf16(acc - bf16_to_f32(hi));
    }
    aggh[idx] = hi;
    aggl[idx] = lo;
}

// ---------------- W1 [36,2048] f32 -> transposed hi/lo bf16 [2048][64] (padded) ----
__global__ void conv_w1(const float* __restrict__ W,
                        u16* __restrict__ Bh, u16* __restrict__ Bl) {
    int idx = blockIdx.x * 256 + threadIdx.x;   // n*64 + k
    if (idx >= H1 * K1PAD) return;
    int n = idx >> 6;
    int k = idx & 63;
    u16 hi = 0, lo = 0;
    if (k < IN_GNN) {
        float v = W[(size_t)k * H1 + n];
        hi = f32_to_bf16(v);
        lo = f32_to_bf16(v - bf16_to_f32(hi));
    }
    Bh[idx] = hi;
    Bl[idx] = lo;
}

// ---------------- W2 [2048,1024] f32 -> transposed hi/lo bf16 [1024,2048] ----------
__global__ __launch_bounds__(256) void conv_w2(const float* __restrict__ W,
                                               u16* __restrict__ Bh,
                                               u16* __restrict__ Bl) {
    __shared__ float t[32][33];
    int bk = blockIdx.x * 32;   // k block
    int bn = blockIdx.y * 32;   // n block
    int tx = threadIdx.x & 31, ty = threadIdx.x >> 5;   // 32 x 8
#pragma unroll
    for (int i = 0; i < 32; i += 8)
        t[ty + i][tx] = W[(size_t)(bk + ty + i) * H2 + bn + tx];
    __syncthreads();
#pragma unroll
    for (int i = 0; i < 32; i += 8) {
        float v = t[tx][ty + i];            // = W[bk+tx][bn+ty+i]
        u16 hi = f32_to_bf16(v);
        u16 lo = f32_to_bf16(v - bf16_to_f32(hi));
        size_t o = (size_t)(bn + ty + i) * H1 + bk + tx;   // Bt[n][k]
        Bh[o] = hi;
        Bl[o] = lo;
    }
}

// ---------------- GEMM1 via bf16 MFMA: agg[rows,64p] @ W1t[2048,64p] + b1, relu ----
__global__ __launch_bounds__(256) void gemm1_mfma(const u16* __restrict__ Ah,
                                                  const u16* __restrict__ Al,
                                                  const u16* __restrict__ Bh,
                                                  const u16* __restrict__ Bl,
                                                  const float* __restrict__ bias,
                                                  u16* __restrict__ Xh,
                                                  u16* __restrict__ Xl,
                                                  int rowbase, int nrows) {
    __shared__ u16 lds[4][128 * K1PAD];   // 16 KB each, 64 KB total
    const int tid  = threadIdx.x;
    const int wid  = tid >> 6;
    const int lane = tid & 63;
    const int wr   = wid >> 1, wc = wid & 1;
    const int row0 = blockIdx.y * 128;          // chunk-local
    const int col0 = blockIdx.x * 128;          // over H1=2048

    const u16* gbase;
    int rbase; bool isA;
    if      (wid == 0) { gbase = Ah; rbase = row0; isA = true; }
    else if (wid == 1) { gbase = Al; rbase = row0; isA = true; }
    else if (wid == 2) { gbase = Bh; rbase = col0; isA = false; }
    else               { gbase = Bl; rbase = col0; isA = false; }
    u16* myl = lds[wid];
    const int r_l  = lane >> 3;        // 0..7 row within 8-row group
    const int ks_l = (lane & 7) * 8;   // k offset
#pragma unroll
    for (int i = 0; i < 16; i++) {
        int r = rbase + i * 8 + r_l;
        if (isA) { int g = rowbase + ((r > nrows - 1) ? (nrows - 1) : r);
                   r = g; }
        const u16* g = gbase + (size_t)r * K1PAD + ks_l;
        __builtin_amdgcn_global_load_lds(
            (const __attribute__((address_space(1))) void*)g,
            (__attribute__((address_space(3))) void*)(myl + i * 512),
            16, 0, 0);
    }
    __syncthreads();   // drains vmcnt; all 4 tiles visible

    f32x4 acc[4][4] = {};
#pragma unroll
    for (int ks = 0; ks < 2; ks++) {
        bf16x8 afh[4], afl[4];
#pragma unroll
        for (int mi = 0; mi < 4; mi++) {
            int r   = wr * 64 + mi * 16 + (lane & 15);
            int off = r * K1PAD + ks * 32 + (lane >> 4) * 8;
            afh[mi] = *(const bf16x8*)&lds[0][off];
            afl[mi] = *(const bf16x8*)&lds[1][off];
        }
#pragma unroll
        for (int ni = 0; ni < 4; ni++) {
            int c   = wc * 64 + ni * 16 + (lane & 15);
            int off = c * K1PAD + ks * 32 + (lane >> 4) * 8;
            bf16x8 bfh = *(const bf16x8*)&lds[2][off];
            bf16x8 bfl = *(const bf16x8*)&lds[3][off];
#pragma unroll
            for (int mi = 0; mi < 4; mi++) {
                acc[mi][ni] = __builtin_amdgcn_mfma_f32_16x16x32_bf16(afh[mi], bfh, acc[mi][ni], 0, 0, 0);
                acc[mi][ni] = __builtin_amdgcn_mfma_f32_16x16x32_bf16(afh[mi], bfl, acc[mi][ni], 0, 0, 0);
                acc[mi][ni] = __builtin_amdgcn_mfma_f32_16x16x32_bf16(afl[mi], bfh, acc[mi][ni], 0, 0, 0);
            }
        }
    }

    // epilogue: bias + relu + hi/lo split; C/D: col=lane&15, row=(lane>>4)*4+j
#pragma unroll
    for (int ni = 0; ni < 4; ni++) {
        int col = col0 + wc * 64 + ni * 16 + (lane & 15);
        float bb = bias[col];
#pragma unroll
        for (int mi = 0; mi < 4; mi++) {
#pragma unroll
            for (int j = 0; j < 4; j++) {
                int lr = row0 + wr * 64 + mi * 16 + (lane >> 4) * 4 + j;
                if (lr < nrows) {
                    float v = fmaxf(acc[mi][ni][j] + bb, 0.0f);
                    u16 hi = f32_to_bf16(v);
                    Xh[(size_t)lr * H1 + col] = hi;
                    Xl[(size_t)lr * H1 + col] = f32_to_bf16(v - bf16_to_f32(hi));
                }
            }
        }
    }
}

// ---------------- GEMM2 via bf16 MFMA (hi/lo split, 3 products) -----------------
// 128x64 tile (grid 16 x panels ~= 1264 blocks -> ~4.9 blocks/CU, kills grid tail).
// 4 waves as 2x2; each wave 64x32 = 4x2 frags. XCD remap: 16 col-blocks of one
// row-panel land on one XCD (A panel L2-resident).
__global__ __launch_bounds__(256) void gemm2_mfma(const u16* __restrict__ Ah,
                                                  const u16* __restrict__ Al,
                                                  const u16* __restrict__ Bh,
                                                  const u16* __restrict__ Bl,
                                                  float* __restrict__ C,
                                                  int rowbase, int nrows) {
    __shared__ u16 ldsAh[128 * 32], ldsAl[128 * 32];   // 8 KB each
    __shared__ u16 ldsBh[64 * 32],  ldsBl[64 * 32];    // 4 KB each
    const int tid  = threadIdx.x;
    const int wid  = tid >> 6;
    const int lane = tid & 63;
    const int wr   = wid >> 1, wc = wid & 1;

    // ---- XCD-aware bijective remap (NB % 8 == 0 guaranteed by grid choice) ----
    int NB = (int)(gridDim.x * gridDim.y);
    int b  = (int)(blockIdx.y * gridDim.x + blockIdx.x);
    int q  = NB >> 3;
    int lin = (b & 7) * q + (b >> 3);
    const int col0 = (lin & 15) * 64;     // 16 col-blocks over H2=1024
    const int row0 = (lin >> 4) * 128;    // chunk-local row panel

    const u16* gbase;
    u16* myl;
    int rbase;
    if      (wid == 0) { gbase = Ah; myl = ldsAh; rbase = row0; }
    else if (wid == 1) { gbase = Al; myl = ldsAl; rbase = row0; }
    else if (wid == 2) { gbase = Bh; myl = ldsBh; rbase = col0; }
    else               { gbase = Bl; myl = ldsBl; rbase = col0; }
    const int r_l  = lane >> 2;        // 0..15
    const int ks_l = (lane & 3) * 8;   // 0,8,16,24  (lds dest byte = lane*16, linear)

    int rows[8];
#pragma unroll
    for (int i = 0; i < 8; i++) {
        int r = rbase + i * 16 + r_l;
        if (wid < 2 && r > nrows - 1) r = nrows - 1;   // clamp A-side reads to chunk
        rows[i] = r;
    }
    const int nstage = (wid < 2) ? 8 : 4;   // A: 128 rows, B: 64 rows

    f32x4 acc[4][2] = {};

    for (int kt = 0; kt < H1 / 32; ++kt) {
        int k0 = kt * 32;
        __syncthreads();   // previous compute done before overwrite
        for (int i = 0; i < nstage; i++) {
            const u16* g = gbase + (size_t)rows[i] * H1 + k0 + ks_l;
            __builtin_amdgcn_global_load_lds(
                (const __attribute__((address_space(1))) void*)g,
                (__attribute__((address_space(3))) void*)(myl + i * 512),
                16, 0, 0);
        }
        __syncthreads();   // compiler drains vmcnt before barrier

        bf16x8 afh[4], afl[4];
#pragma unroll
        for (int mi = 0; mi < 4; mi++) {
            int r   = wr * 64 + mi * 16 + (lane & 15);
            int off = r * 32 + (lane >> 4) * 8;
            afh[mi] = *(const bf16x8*)&ldsAh[off];
            afl[mi] = *(const bf16x8*)&ldsAl[off];
        }
#pragma unroll
        for (int ni = 0; ni < 2; ni++) {
            int c   = wc * 32 + ni * 16 + (lane & 15);
            int off = c * 32 + (lane >> 4) * 8;
            bf16x8 bfh = *(const bf16x8*)&ldsBh[off];
            bf16x8 bfl = *(const bf16x8*)&ldsBl[off];
#pragma unroll
            for (int mi = 0; mi < 4; mi++) {
                acc[mi][ni] = __builtin_amdgcn_mfma_f32_16x16x32_bf16(afh[mi], bfh, acc[mi][ni], 0, 0, 0);
                acc[mi][ni] = __builtin_amdgcn_mfma_f32_16x16x32_bf16(afh[mi], bfl, acc[mi][ni], 0, 0, 0);
                acc[mi][ni] = __builtin_amdgcn_mfma_f32_16x16x32_bf16(afl[mi], bfh, acc[mi][ni], 0, 0, 0);
            }
        }
    }

    // C/D layout: col = lane&15, row = (lane>>4)*4 + j  [m89/m91 verified]
#pragma unroll
    for (int mi = 0; mi < 4; mi++) {
#pragma unroll
        for (int ni = 0; ni < 2; ni++) {
            int col = col0 + wc * 32 + ni * 16 + (lane & 15);
#pragma unroll
            for (int j = 0; j < 4; j++) {
                int lr = row0 + wr * 64 + mi * 16 + (lane >> 4) * 4 + j;
                if (lr < nrows) C[(size_t)(rowbase + lr) * H2 + col] = acc[mi][ni][j];
            }
        }
    }
}

// ---------------- layer-2 aggregation via CSR gather (1024-dim), bias+relu fused ----
__global__ __launch_bounds__(256) void agg_csr_1024(const int* __restrict__ off,
                                                    const int* __restrict__ csr_src,
                                                    const float* __restrict__ csr_nrm,
                                                    const float* __restrict__ xw,
                                                    const float* __restrict__ b,
                                                    float* __restrict__ x2) {
    int node = blockIdx.x;
    int p0 = off[node], p1 = off[node + 1];
    int d = threadIdx.x;             // float4 lane: 256 x 4 = 1024 dims
    float4 a0 = make_float4(0.f, 0.f, 0.f, 0.f);
    float4 a1 = make_float4(0.f, 0.f, 0.f, 0.f);
    int p = p0;
    for (; p + 1 < p1; p += 2) {
        int   s0 = csr_src[p],     s1 = csr_src[p + 1];
        float n0 = csr_nrm[p],     n1 = csr_nrm[p + 1];
        float4 v0 = ((const float4*)&xw[(size_t)s0 * H2])[d];
        float4 v1 = ((const float4*)&xw[(size_t)s1 * H2])[d];
        a0.x += v0.x * n0; a0.y += v0.y * n0; a0.z += v0.z * n0; a0.w += v0.w * n0;
        a1.x += v1.x * n1; a1.y += v1.y * n1; a1.z += v1.z * n1; a1.w += v1.w * n1;
    }
    if (p < p1) {
        int   s0 = csr_src[p];
        float n0 = csr_nrm[p];
        float4 v0 = ((const float4*)&xw[(size_t)s0 * H2])[d];
        a0.x += v0.x * n0; a0.y += v0.y * n0; a0.z += v0.z * n0; a0.w += v0.w * n0;
    }
    float4 bb = ((const float4*)b)[d];
    float4 o;
    o.x = fmaxf(a0.x + a1.x + bb.x, 0.f);
    o.y = fmaxf(a0.y + a1.y + bb.y, 0.f);
    o.z = fmaxf(a0.z + a1.z + bb.z, 0.f);
    o.w = fmaxf(a0.w + a1.w + bb.w, 0.f);
    ((float4*)&x2[(size_t)node * H2])[d] = o;
}

// ---------------- pooling ----------------
__global__ void cnt_accum(const int* __restrict__ batch, float* cnt) {
    int i = blockIdx.x * 256 + threadIdx.x;
    if (i < N_NODES) atomicAdd(&cnt[batch[i]], 1.0f);
}

__global__ void pool_accum(const int* __restrict__ batch, const float* __restrict__ x2,
                           float* __restrict__ pooled) {
    int d  = blockIdx.x * 256 + threadIdx.x;   // 0..1023
    int i0 = blockIdx.y * 64;
    float acc = 0.0f;
    int gprev = -1;
    for (int i = 0; i < 64; i++) {
        int node = i0 + i;
        if (node >= N_NODES) break;
        int g = batch[node];
        if (g != gprev) {
            if (gprev >= 0) atomicAdd(&pooled[gprev * H2 + d], acc);
            acc = 0.0f; gprev = g;
        }
        acc += x2[(size_t)node * H2 + d];
    }
    if (gprev >= 0) atomicAdd(&pooled[gprev * H2 + d], acc);
}

__global__ void pool_norm(float* pooled, const float* cnt) {
    int idx = blockIdx.x * 256 + threadIdx.x;
    if (idx < N_GRAPHS * H2) {
        int g = idx >> 10;
        pooled[idx] /= fmaxf(cnt[g], 1.0f);
    }
}

// ---------------- MLP head: fused non-atomic GEMM (k-loop inside), bias+opt-relu ---
__global__ __launch_bounds__(256) void head_fused(const float* __restrict__ In,
                                                  const float* __restrict__ W,
                                                  const float* __restrict__ bias,
                                                  float* __restrict__ Out,
                                                  int K, int N, int relu) {
    __shared__ __align__(16) float As[16][256];
    int n  = blockIdx.x * 256 + threadIdx.x;
    int m0 = blockIdx.y * 16;
    float acc[16] = {};
    for (int k0 = 0; k0 < K; k0 += 256) {
        __syncthreads();
        for (int t = threadIdx.x; t < 16 * 256; t += 256) {
            int r = t >> 8, k = t & 255;
            As[r][k] = In[(size_t)(m0 + r) * K + k0 + k];
        }
        __syncthreads();
        for (int k = 0; k < 256; k += 4) {
            float w0 = W[(size_t)(k0 + k + 0) * N + n];
            float w1 = W[(size_t)(k0 + k + 1) * N + n];
            float w2 = W[(size_t)(k0 + k + 2) * N + n];
            float w3 = W[(size_t)(k0 + k + 3) * N + n];
#pragma unroll
            for (int r = 0; r < 16; r++) {
                float4 a = *(const float4*)&As[r][k];
                acc[r] += a.x * w0 + a.y * w1 + a.z * w2 + a.w * w3;
            }
        }
    }
    float bb = bias[n];
    for (int r = 0; r < 16; r++) {
        float v = acc[r] + bb;
        if (relu) v = fmaxf(v, 0.0f);
        Out[(size_t)(m0 + r) * N + n] = v;
    }
}

__global__ void head3(const float* __restrict__ h2, const float* __restrict__ oW,
                      const float* __restrict__ ob, float* __restrict__ out) {
    int tid = threadIdx.x;          // 128 threads: m = tid/2, c = tid&1
    if (tid >= 128) return;
    int m = tid >> 1, c = tid & 1;
    float acc = 0.0f;
    for (int k = 0; k < 512; k++) acc += h2[m * 512 + k] * oW[k * 2 + c];
    out[tid] = acc + ob[c];
}

// ---------------- host ----------------
extern "C" void kernel_launch(void* const* d_in, const int* in_sizes, int n_in,
                              void* d_out, int out_size, void* d_ws, size_t ws_size,
                              hipStream_t stream) {
    const int*   ids   = (const int*)d_in[0];
    const float* other = (const float*)d_in[1];
    const int*   ei    = (const int*)d_in[2];
    const int*   batch = (const int*)d_in[3];
    const float* emb   = (const float*)d_in[4];
    const float* W1    = (const float*)d_in[5];
    const float* b1    = (const float*)d_in[6];
    const float* W2    = (const float*)d_in[7];
    const float* b2    = (const float*)d_in[8];
    const float* hW1   = (const float*)d_in[9];
    const float* hb1   = (const float*)d_in[10];
    const float* hW2   = (const float*)d_in[11];
    const float* hb2   = (const float*)d_in[12];
    const float* oW    = (const float*)d_in[13];
    const float* ob    = (const float*)d_in[14];
    float* out = (float*)d_out;

    char* ws = (char*)d_ws;
    size_t off_b = 0;
    auto alloc = [&](size_t bytes) {
        size_t p = (off_b + 255) & ~(size_t)255;
        off_b = p + bytes;
        return p;
    };
    // total ~186 MB (R2-proven budget 254 MB; R3's 262 MB died)
    size_t o_dinv = alloc((size_t)N_NODES * 4);
    size_t o_indeg= alloc((size_t)(N_NODES + 1) * 4);
    size_t o_off  = alloc((size_t)(N_NODES + 1) * 4);
    size_t o_cur  = alloc((size_t)N_NODES * 4);
    size_t o_csrc = alloc((size_t)N_TOT_E * 4);
    size_t o_cnrm = alloc((size_t)N_TOT_E * 4);
    size_t o_xf   = alloc((size_t)N_NODES * IN_GNN * 4);
    size_t o_aggh = alloc((size_t)N_NODES * K1PAD * 2);  // bf16 hi, padded
    size_t o_aggl = alloc((size_t)N_NODES * K1PAD * 2);  // bf16 lo
    size_t o_w1h  = alloc((size_t)H1 * K1PAD * 2);       // W1^T hi bf16 [2048][64]
    size_t o_w1l  = alloc((size_t)H1 * K1PAD * 2);
    size_t o_x1h  = alloc((size_t)CHUNK0 * H1 * 2);      // chunk-local bf16 hi
    size_t o_x1l  = alloc((size_t)CHUNK0 * H1 * 2);      // chunk-local bf16 lo
    size_t o_w2h  = alloc((size_t)H2 * H1 * 2);          // W2^T hi bf16 [1024][2048]
    size_t o_w2l  = alloc((size_t)H2 * H1 * 2);
    size_t o_xw2  = alloc((size_t)N_NODES * H2 * 4);
    size_t o_pool = alloc((size_t)N_GRAPHS * H2 * 4);
    size_t o_cnt  = alloc((size_t)N_GRAPHS * 4);
    size_t o_h1   = alloc((size_t)N_GRAPHS * 1024 * 4);
    size_t o_h2   = alloc((size_t)N_GRAPHS * 512 * 4);

    float* dinv = (float*)(ws + o_dinv);
    int*   indeg= (int*)(ws + o_indeg);
    int*   offs = (int*)(ws + o_off);
    int*   cur  = (int*)(ws + o_cur);
    int*   csrc = (int*)(ws + o_csrc);
    float* cnrm = (float*)(ws + o_cnrm);
    float* xf   = (float*)(ws + o_xf);
    u16*   aggh = (u16*)(ws + o_aggh);
    u16*   aggl = (u16*)(ws + o_aggl);
    u16*   w1h  = (u16*)(ws + o_w1h);
    u16*   w1l  = (u16*)(ws + o_w1l);
    u16*   x1h  = (u16*)(ws + o_x1h);
    u16*   x1l  = (u16*)(ws + o_x1l);
    u16*   w2h  = (u16*)(ws + o_w2h);
    u16*   w2l  = (u16*)(ws + o_w2l);
    float* xw2  = (float*)(ws + o_xw2);
    // x2 aliases the x1h+x1l region (82.8 MB contiguous >= 80 MB; both dead then)
    float* x2   = (float*)(ws + o_x1h);
    float* pooled = (float*)(ws + o_pool);
    float* cnt  = (float*)(ws + o_cnt);
    float* h1   = (float*)(ws + o_h1);
    float* h2   = (float*)(ws + o_h2);

    // indegree (int); self loop = init 1; dinv = rsqrt(deg)
    fill_i32<<<(N_NODES + 255) / 256, 256, 0, stream>>>(indeg, 1, N_NODES);
    deg_accum<<<(N_EDGES + 255) / 256, 256, 0, stream>>>(ei, indeg);
    deg_to_dinv<<<(N_NODES + 255) / 256, 256, 0, stream>>>(indeg, dinv);

    // CSR
    scan_offsets<<<1, 1024, 0, stream>>>(indeg, offs, cur);
    csr_fill<<<(N_TOT_E + 255) / 256, 256, 0, stream>>>(ei, dinv, cur, csrc, cnrm);

    // node features + layer-1 aggregation (full graph) -> padded hi/lo bf16
    build_xfeat<<<(N_NODES * IN_GNN + 255) / 256, 256, 0, stream>>>(ids, other, emb, xf);
    agg_csr_36<<<(N_NODES * K1PAD + 255) / 256, 256, 0, stream>>>(offs, csrc, cnrm, xf, aggh, aggl);

    // weights -> transposed hi/lo bf16 (once)
    conv_w1<<<(H1 * K1PAD + 255) / 256, 256, 0, stream>>>(W1, w1h, w1l);
    conv_w2<<<dim3(H1 / 32, H2 / 32), 256, 0, stream>>>(W2, w2h, w2l);

    // layers 1+2 GEMMs in two M-chunks to bound workspace
    {
        const int c0 = CHUNK0, c1 = N_NODES - CHUNK0;   // 10112, 9888
        // chunk 0 (79 panels): gemm2 grid 16 x 79 = 1264 (% 8 == 0)
        gemm1_mfma<<<dim3(H1 / 128, c0 / 128), 256, 0, stream>>>(aggh, aggl, w1h, w1l, b1, x1h, x1l, 0, c0);
        gemm2_mfma<<<dim3(16, c0 / 128), 256, 0, stream>>>(x1h, x1l, w2h, w2l, xw2, 0, c0);
        // chunk 1 (78 panels): grid 16 x 78 = 1248 (% 8 == 0)
        gemm1_mfma<<<dim3(H1 / 128, (c1 + 127) / 128), 256, 0, stream>>>(aggh, aggl, w1h, w1l, b1, x1h, x1l, c0, c1);
        gemm2_mfma<<<dim3(16, (c1 + 127) / 128), 256, 0, stream>>>(x1h, x1l, w2h, w2l, xw2, c0, c1);
    }

    // layer-2 aggregation with bias+relu fused (x2 overwrites dead x1h/x1l region)
    agg_csr_1024<<<N_NODES, 256, 0, stream>>>(offs, csrc, cnrm, xw2, b2, x2);

    // mean pool
    hipMemsetAsync(pooled, 0, (size_t)N_GRAPHS * H2 * 4, stream);
    hipMemsetAsync(cnt, 0, (size_t)N_GRAPHS * 4, stream);
    cnt_accum<<<(N_NODES + 255) / 256, 256, 0, stream>>>(batch, cnt);
    pool_accum<<<dim3(H2 / 256, (N_NODES + 63) / 64), 256, 0, stream>>>(batch, x2, pooled);
    pool_norm<<<(N_GRAPHS * H2 + 255) / 256, 256, 0, stream>>>(pooled, cnt);

    // head: fused non-atomic GEMMs
    head_fused<<<dim3(1024 / 256, N_GRAPHS / 16), 256, 0, stream>>>(pooled, hW1, hb1, h1, 1024, 1024, 1);
    head_fused<<<dim3(512 / 256, N_GRAPHS / 16), 256, 0, stream>>>(h1, hW2, hb2, h2, 1024, 512, 1);
    head3<<<1, 128, 0, stream>>>(h2, oW, ob, out);
}

// Round 9
// 1057.331 us; speedup vs baseline: 1.1817x; 1.1817x over previous
//
#include <hip/hip_runtime.h>
#include <hip/hip_bf16.h>

#define N_NODES  20000
#define N_EDGES  160000
#define N_TOT_E  180000   // edges + self loops
#define N_GRAPHS 64
#define EMBED_DIM 32
#define IN_GNN   36
#define K1PAD    64       // gemm1 K padded for MFMA
#define H1       2048
#define H2       1024
#define CHUNK0   10112    // 79 * 128; chunk1 = 9888 = N_NODES - CHUNK0

typedef unsigned short u16;
typedef short bf16x8 __attribute__((ext_vector_type(8)));
typedef float f32x4  __attribute__((ext_vector_type(4)));

__device__ inline u16 f32_to_bf16(float f) {
    union { float f; unsigned u; } v; v.f = f;
    unsigned lsb = (v.u >> 16) & 1u;
    return (u16)((v.u + 0x7fffu + lsb) >> 16);
}
__device__ inline float bf16_to_f32(u16 h) {
    union { unsigned u; float f; } v; v.u = ((unsigned)h) << 16;
    return v.f;
}

// ---------------- small utility kernels ----------------

__global__ void fill_i32(int* p, int v, int n) {
    int i = blockIdx.x * 256 + threadIdx.x;
    if (i < n) p[i] = v;
}

__global__ void deg_accum(const int* __restrict__ ei, int* indeg) {
    int e = blockIdx.x * 256 + threadIdx.x;
    if (e < N_EDGES) atomicAdd(&indeg[ei[N_EDGES + e]], 1);
}

__global__ void deg_to_dinv(const int* __restrict__ indeg, float* __restrict__ d) {
    int i = blockIdx.x * 256 + threadIdx.x;
    if (i < N_NODES) d[i] = rsqrtf((float)indeg[i]);   // deg >= 1 (self loop)
}

__global__ void build_xfeat(const int* __restrict__ ids, const float* __restrict__ other,
                            const float* __restrict__ emb, float* __restrict__ xf) {
    int idx = blockIdx.x * 256 + threadIdx.x;   // node*36 + d
    if (idx >= N_NODES * IN_GNN) return;
    int i = idx / IN_GNN;
    int d = idx - i * IN_GNN;
    float v = (d < EMBED_DIM) ? emb[(size_t)ids[i] * EMBED_DIM + d]
                              : other[i * 4 + (d - EMBED_DIM)];
    xf[idx] = v;
}

// ---------------- CSR build: fast single-block scan via wave shuffles ------------
__global__ __launch_bounds__(1024) void scan_offsets(const int* __restrict__ indeg,
                                                     int* __restrict__ off,
                                                     int* __restrict__ cursor) {
    __shared__ int wsum[16];
    int tid = threadIdx.x;
    int lane = tid & 63, wid = tid >> 6;
    int base = 0;
    for (int start = 0; start < N_NODES; start += 1024) {
        int i = start + tid;
        int v = (i < N_NODES) ? indeg[i] : 0;
        int x = v;
#pragma unroll
        for (int d = 1; d < 64; d <<= 1) {
            int y = __shfl_up(x, d);
            if (lane >= d) x += y;
        }
        if (lane == 63) wsum[wid] = x;
        __syncthreads();
        if (wid == 0 && lane < 16) {
            int w = wsum[lane];
#pragma unroll
            for (int d = 1; d < 16; d <<= 1) {
                int y = __shfl_up(w, d, 16);
                if ((lane & 15) >= d) w += y;
            }
            wsum[lane] = w;
        }
        __syncthreads();
        int incl = x + (wid > 0 ? wsum[wid - 1] : 0);
        int excl = base + incl - v;
        if (i < N_NODES) { off[i] = excl; cursor[i] = excl; }
        int total = wsum[15];
        __syncthreads();   // protect wsum before next iteration overwrites
        base += total;
    }
    if (tid == 0) off[N_NODES] = N_TOT_E;
}

__global__ void csr_fill(const int* __restrict__ ei, const float* __restrict__ dinv,
                         int* __restrict__ cursor,
                         int* __restrict__ csr_src, float* __restrict__ csr_nrm) {
    int e = blockIdx.x * 256 + threadIdx.x;
    if (e >= N_TOT_E) return;
    int s, t;
    if (e < N_EDGES) { s = ei[e]; t = ei[N_EDGES + e]; }
    else             { s = t = e - N_EDGES; }
    int pos = atomicAdd(&cursor[t], 1);
    csr_src[pos] = s;
    csr_nrm[pos] = dinv[s] * dinv[t];
}

// ---------------- layer-1 aggregation via CSR gather -> hi/lo bf16, [node][64] padded
__global__ void agg_csr_36(const int* __restrict__ off, const int* __restrict__ csr_src,
                           const float* __restrict__ csr_nrm,
                           const float* __restrict__ xf,
                           u16* __restrict__ aggh, u16* __restrict__ aggl) {
    int idx = blockIdx.x * 256 + threadIdx.x;   // node*64 + d
    if (idx >= N_NODES * K1PAD) return;
    int node = idx >> 6;
    int d = idx & 63;
    u16 hi = 0, lo = 0;
    if (d < IN_GNN) {
        int p0 = off[node], p1 = off[node + 1];
        float acc = 0.0f;
        for (int p = p0; p < p1; p++)
            acc += xf[csr_src[p] * IN_GNN + d] * csr_nrm[p];
        hi = f32_to_bf16(acc);
        lo = f32_to_bf16(acc - bf16_to_f32(hi));
    }
    aggh[idx] = hi;
    aggl[idx] = lo;
}

// ---------------- W1 [36,2048] f32 -> transposed hi/lo bf16 [2048][64] (padded) ----
__global__ void conv_w1(const float* __restrict__ W,
                        u16* __restrict__ Bh, u16* __restrict__ Bl) {
    int idx = blockIdx.x * 256 + threadIdx.x;   // n*64 + k
    if (idx >= H1 * K1PAD) return;
    int n = idx >> 6;
    int k = idx & 63;
    u16 hi = 0, lo = 0;
    if (k < IN_GNN) {
        float v = W[(size_t)k * H1 + n];
        hi = f32_to_bf16(v);
        lo = f32_to_bf16(v - bf16_to_f32(hi));
    }
    Bh[idx] = hi;
    Bl[idx] = lo;
}

// ---------------- W2 [2048,1024] f32 -> transposed hi/lo bf16 [1024,2048] ----------
__global__ __launch_bounds__(256) void conv_w2(const float* __restrict__ W,
                                               u16* __restrict__ Bh,
                                               u16* __restrict__ Bl) {
    __shared__ float t[32][33];
    int bk = blockIdx.x * 32;   // k block
    int bn = blockIdx.y * 32;   // n block
    int tx = threadIdx.x & 31, ty = threadIdx.x >> 5;   // 32 x 8
#pragma unroll
    for (int i = 0; i < 32; i += 8)
        t[ty + i][tx] = W[(size_t)(bk + ty + i) * H2 + bn + tx];
    __syncthreads();
#pragma unroll
    for (int i = 0; i < 32; i += 8) {
        float v = t[tx][ty + i];            // = W[bk+tx][bn+ty+i]
        u16 hi = f32_to_bf16(v);
        u16 lo = f32_to_bf16(v - bf16_to_f32(hi));
        size_t o = (size_t)(bn + ty + i) * H1 + bk + tx;   // Bt[n][k]
        Bh[o] = hi;
        Bl[o] = lo;
    }
}

// ---------------- GEMM1 via bf16 MFMA: agg[rows,64p] @ W1t[2048,64p] + b1, relu ----
__global__ __launch_bounds__(256) void gemm1_mfma(const u16* __restrict__ Ah,
                                                  const u16* __restrict__ Al,
                                                  const u16* __restrict__ Bh,
                                                  const u16* __restrict__ Bl,
                                                  const float* __restrict__ bias,
                                                  u16* __restrict__ Xh,
                                                  u16* __restrict__ Xl,
                                                  int rowbase, int nrows) {
    __shared__ u16 lds[4][128 * K1PAD];   // 16 KB each, 64 KB total
    const int tid  = threadIdx.x;
    const int wid  = tid >> 6;
    const int lane = tid & 63;
    const int wr   = wid >> 1, wc = wid & 1;
    const int row0 = blockIdx.y * 128;          // chunk-local
    const int col0 = blockIdx.x * 128;          // over H1=2048

    const u16* gbase;
    int rbase; bool isA;
    if      (wid == 0) { gbase = Ah; rbase = row0; isA = true; }
    else if (wid == 1) { gbase = Al; rbase = row0; isA = true; }
    else if (wid == 2) { gbase = Bh; rbase = col0; isA = false; }
    else               { gbase = Bl; rbase = col0; isA = false; }
    u16* myl = lds[wid];
    const int r_l  = lane >> 3;        // 0..7 row within 8-row group
    const int ks_l = (lane & 7) * 8;   // k offset
#pragma unroll
    for (int i = 0; i < 16; i++) {
        int r = rbase + i * 8 + r_l;
        if (isA) { int g = rowbase + ((r > nrows - 1) ? (nrows - 1) : r);
                   r = g; }
        const u16* g = gbase + (size_t)r * K1PAD + ks_l;
        __builtin_amdgcn_global_load_lds(
            (const __attribute__((address_space(1))) void*)g,
            (__attribute__((address_space(3))) void*)(myl + i * 512),
            16, 0, 0);
    }
    __syncthreads();   // drains vmcnt; all 4 tiles visible

    f32x4 acc[4][4] = {};
#pragma unroll
    for (int ks = 0; ks < 2; ks++) {
        bf16x8 afh[4], afl[4];
#pragma unroll
        for (int mi = 0; mi < 4; mi++) {
            int r   = wr * 64 + mi * 16 + (lane & 15);
            int off = r * K1PAD + ks * 32 + (lane >> 4) * 8;
            afh[mi] = *(const bf16x8*)&lds[0][off];
            afl[mi] = *(const bf16x8*)&lds[1][off];
        }
#pragma unroll
        for (int ni = 0; ni < 4; ni++) {
            int c   = wc * 64 + ni * 16 + (lane & 15);
            int off = c * K1PAD + ks * 32 + (lane >> 4) * 8;
            bf16x8 bfh = *(const bf16x8*)&lds[2][off];
            bf16x8 bfl = *(const bf16x8*)&lds[3][off];
#pragma unroll
            for (int mi = 0; mi < 4; mi++) {
                acc[mi][ni] = __builtin_amdgcn_mfma_f32_16x16x32_bf16(afh[mi], bfh, acc[mi][ni], 0, 0, 0);
                acc[mi][ni] = __builtin_amdgcn_mfma_f32_16x16x32_bf16(afh[mi], bfl, acc[mi][ni], 0, 0, 0);
                acc[mi][ni] = __builtin_amdgcn_mfma_f32_16x16x32_bf16(afl[mi], bfh, acc[mi][ni], 0, 0, 0);
            }
        }
    }

    // epilogue: bias + relu + hi/lo split; C/D: col=lane&15, row=(lane>>4)*4+j
#pragma unroll
    for (int ni = 0; ni < 4; ni++) {
        int col = col0 + wc * 64 + ni * 16 + (lane & 15);
        float bb = bias[col];
#pragma unroll
        for (int mi = 0; mi < 4; mi++) {
#pragma unroll
            for (int j = 0; j < 4; j++) {
                int lr = row0 + wr * 64 + mi * 16 + (lane >> 4) * 4 + j;
                if (lr < nrows) {
                    float v = fmaxf(acc[mi][ni][j] + bb, 0.0f);
                    u16 hi = f32_to_bf16(v);
                    Xh[(size_t)lr * H1 + col] = hi;
                    Xl[(size_t)lr * H1 + col] = f32_to_bf16(v - bf16_to_f32(hi));
                }
            }
        }
    }
}

// ---------------- GEMM2 via bf16 MFMA (hi/lo split, 3 products) -----------------
// R6-proven: 128x128 tile, BK=32, 4 waves. XCD remap keeps one A row-panel per XCD.
// (R7's 128x64 tile regressed: staging bytes/MFMA doubled -> MfmaUtil 38->25%.)
__global__ __launch_bounds__(256) void gemm2_mfma(const u16* __restrict__ Ah,
                                                  const u16* __restrict__ Al,
                                                  const u16* __restrict__ Bh,
                                                  const u16* __restrict__ Bl,
                                                  float* __restrict__ C,
                                                  int rowbase, int nrows) {
    __shared__ u16 lds[4][128 * 32];   // Ah, Al, Bh, Bl tiles: 8 KB each
    const int tid  = threadIdx.x;
    const int wid  = tid >> 6;
    const int lane = tid & 63;
    const int wr   = wid >> 1, wc = wid & 1;

    // ---- XCD-aware bijective remap (grid NB % 8 == 0) ----
    int NB = (int)(gridDim.x * gridDim.y);
    int b  = (int)(blockIdx.y * gridDim.x + blockIdx.x);
    int lin = b;
    if ((NB & 7) == 0) {
        int xcd = b & 7, j = b >> 3;      // round-robin slot -> contiguous run
        lin = xcd * (NB >> 3) + j;
    }
    const int col0 = (lin & 7) * 128;
    const int row0 = (lin >> 3) * 128;    // chunk-local

    const u16* gbase;
    int rbase;
    if      (wid == 0) { gbase = Ah; rbase = row0; }
    else if (wid == 1) { gbase = Al; rbase = row0; }
    else if (wid == 2) { gbase = Bh; rbase = col0; }
    else               { gbase = Bl; rbase = col0; }
    u16* myl = lds[wid];
    const int r_l  = lane >> 2;        // 0..15
    const int ks_l = (lane & 3) * 8;   // 0,8,16,24  (lds dest byte = lane*16, linear)

    int rows[8];
#pragma unroll
    for (int i = 0; i < 8; i++) {
        int r = rbase + i * 16 + r_l;
        if (wid < 2 && r > nrows - 1) r = nrows - 1;   // clamp A-side reads to chunk
        rows[i] = r;
    }

    f32x4 acc[4][4] = {};

    for (int kt = 0; kt < H1 / 32; ++kt) {
        int k0 = kt * 32;
        __syncthreads();   // previous compute done before overwrite
#pragma unroll
        for (int i = 0; i < 8; i++) {
            const u16* g = gbase + (size_t)rows[i] * H1 + k0 + ks_l;
            __builtin_amdgcn_global_load_lds(
                (const __attribute__((address_space(1))) void*)g,
                (__attribute__((address_space(3))) void*)(myl + i * 512),
                16, 0, 0);
        }
        __syncthreads();   // compiler drains vmcnt before barrier

        bf16x8 afh[4], afl[4];
#pragma unroll
        for (int mi = 0; mi < 4; mi++) {
            int r   = wr * 64 + mi * 16 + (lane & 15);
            int off = r * 32 + (lane >> 4) * 8;
            afh[mi] = *(const bf16x8*)&lds[0][off];
            afl[mi] = *(const bf16x8*)&lds[1][off];
        }
#pragma unroll
        for (int ni = 0; ni < 4; ni++) {
            int c   = wc * 64 + ni * 16 + (lane & 15);
            int off = c * 32 + (lane >> 4) * 8;
            bf16x8 bfh = *(const bf16x8*)&lds[2][off];
            bf16x8 bfl = *(const bf16x8*)&lds[3][off];
#pragma unroll
            for (int mi = 0; mi < 4; mi++) {
                acc[mi][ni] = __builtin_amdgcn_mfma_f32_16x16x32_bf16(afh[mi], bfh, acc[mi][ni], 0, 0, 0);
                acc[mi][ni] = __builtin_amdgcn_mfma_f32_16x16x32_bf16(afh[mi], bfl, acc[mi][ni], 0, 0, 0);
                acc[mi][ni] = __builtin_amdgcn_mfma_f32_16x16x32_bf16(afl[mi], bfh, acc[mi][ni], 0, 0, 0);
            }
        }
    }

    // C/D layout: col = lane&15, row = (lane>>4)*4 + j  [m89/m91 verified]
#pragma unroll
    for (int mi = 0; mi < 4; mi++) {
#pragma unroll
        for (int ni = 0; ni < 4; ni++) {
            int col = col0 + wc * 64 + ni * 16 + (lane & 15);
#pragma unroll
            for (int j = 0; j < 4; j++) {
                int lr = row0 + wr * 64 + mi * 16 + (lane >> 4) * 4 + j;
                if (lr < nrows) C[(size_t)(rowbase + lr) * H2 + col] = acc[mi][ni][j];
            }
        }
    }
}

// ---------------- layer-2 aggregation via CSR gather (1024-dim), bias+relu fused ----
__global__ __launch_bounds__(256) void agg_csr_1024(const int* __restrict__ off,
                                                    const int* __restrict__ csr_src,
                                                    const float* __restrict__ csr_nrm,
                                                    const float* __restrict__ xw,
                                                    const float* __restrict__ b,
                                                    float* __restrict__ x2) {
    int node = blockIdx.x;
    int p0 = off[node], p1 = off[node + 1];
    int d = threadIdx.x;             // float4 lane: 256 x 4 = 1024 dims
    float4 a0 = make_float4(0.f, 0.f, 0.f, 0.f);
    float4 a1 = make_float4(0.f, 0.f, 0.f, 0.f);
    int p = p0;
    for (; p + 1 < p1; p += 2) {
        int   s0 = csr_src[p],     s1 = csr_src[p + 1];
        float n0 = csr_nrm[p],     n1 = csr_nrm[p + 1];
        float4 v0 = ((const float4*)&xw[(size_t)s0 * H2])[d];
        float4 v1 = ((const float4*)&xw[(size_t)s1 * H2])[d];
        a0.x += v0.x * n0; a0.y += v0.y * n0; a0.z += v0.z * n0; a0.w += v0.w * n0;
        a1.x += v1.x * n1; a1.y += v1.y * n1; a1.z += v1.z * n1; a1.w += v1.w * n1;
    }
    if (p < p1) {
        int   s0 = csr_src[p];
        float n0 = csr_nrm[p];
        float4 v0 = ((const float4*)&xw[(size_t)s0 * H2])[d];
        a0.x += v0.x * n0; a0.y += v0.y * n0; a0.z += v0.z * n0; a0.w += v0.w * n0;
    }
    float4 bb = ((const float4*)b)[d];
    float4 o;
    o.x = fmaxf(a0.x + a1.x + bb.x, 0.f);
    o.y = fmaxf(a0.y + a1.y + bb.y, 0.f);
    o.z = fmaxf(a0.z + a1.z + bb.z, 0.f);
    o.w = fmaxf(a0.w + a1.w + bb.w, 0.f);
    ((float4*)&x2[(size_t)node * H2])[d] = o;
}

// ---------------- pooling ----------------
__global__ void cnt_accum(const int* __restrict__ batch, float* cnt) {
    int i = blockIdx.x * 256 + threadIdx.x;
    if (i < N_NODES) atomicAdd(&cnt[batch[i]], 1.0f);
}

__global__ void pool_accum(const int* __restrict__ batch, const float* __restrict__ x2,
                           float* __restrict__ pooled) {
    int d  = blockIdx.x * 256 + threadIdx.x;   // 0..1023
    int i0 = blockIdx.y * 64;
    float acc = 0.0f;
    int gprev = -1;
    for (int i = 0; i < 64; i++) {
        int node = i0 + i;
        if (node >= N_NODES) break;
        int g = batch[node];
        if (g != gprev) {
            if (gprev >= 0) atomicAdd(&pooled[gprev * H2 + d], acc);
            acc = 0.0f; gprev = g;
        }
        acc += x2[(size_t)node * H2 + d];
    }
    if (gprev >= 0) atomicAdd(&pooled[gprev * H2 + d], acc);
}

__global__ void pool_norm(float* pooled, const float* cnt) {
    int idx = blockIdx.x * 256 + threadIdx.x;
    if (idx < N_GRAPHS * H2) {
        int g = idx >> 10;
        pooled[idx] /= fmaxf(cnt[g], 1.0f);
    }
}

// ---------------- MLP head: fused non-atomic GEMM (k-loop inside), bias+opt-relu ---
__global__ __launch_bounds__(256) void head_fused(const float* __restrict__ In,
                                                  const float* __restrict__ W,
                                                  const float* __restrict__ bias,
                                                  float* __restrict__ Out,
                                                  int K, int N, int relu) {
    __shared__ __align__(16) float As[8][256];
    int n  = blockIdx.x * 256 + threadIdx.x;
    int m0 = blockIdx.y * 8;
    float acc[8] = {};
    for (int k0 = 0; k0 < K; k0 += 256) {
        __syncthreads();
        for (int t = threadIdx.x; t < 8 * 256; t += 256) {
            int r = t >> 8, k = t & 255;
            As[r][k] = In[(size_t)(m0 + r) * K + k0 + k];
        }
        __syncthreads();
        for (int k = 0; k < 256; k += 4) {
            float w0 = W[(size_t)(k0 + k + 0) * N + n];
            float w1 = W[(size_t)(k0 + k + 1) * N + n];
            float w2 = W[(size_t)(k0 + k + 2) * N + n];
            float w3 = W[(size_t)(k0 + k + 3) * N + n];
#pragma unroll
            for (int r = 0; r < 8; r++) {
                float4 a = *(const float4*)&As[r][k];
                acc[r] += a.x * w0 + a.y * w1 + a.z * w2 + a.w * w3;
            }
        }
    }
    float bb = bias[n];
    for (int r = 0; r < 8; r++) {
        float v = acc[r] + bb;
        if (relu) v = fmaxf(v, 0.0f);
        Out[(size_t)(m0 + r) * N + n] = v;
    }
}

__global__ void head3(const float* __restrict__ h2, const float* __restrict__ oW,
                      const float* __restrict__ ob, float* __restrict__ out) {
    int tid = threadIdx.x;          // 128 threads: m = tid/2, c = tid&1
    if (tid >= 128) return;
    int m = tid >> 1, c = tid & 1;
    float acc = 0.0f;
    for (int k = 0; k < 512; k++) acc += h2[m * 512 + k] * oW[k * 2 + c];
    out[tid] = acc + ob[c];
}

// ---------------- host ----------------
extern "C" void kernel_launch(void* const* d_in, const int* in_sizes, int n_in,
                              void* d_out, int out_size, void* d_ws, size_t ws_size,
                              hipStream_t stream) {
    const int*   ids   = (const int*)d_in[0];
    const float* other = (const float*)d_in[1];
    const int*   ei    = (const int*)d_in[2];
    const int*   batch = (const int*)d_in[3];
    const float* emb   = (const float*)d_in[4];
    const float* W1    = (const float*)d_in[5];
    const float* b1    = (const float*)d_in[6];
    const float* W2    = (const float*)d_in[7];
    const float* b2    = (const float*)d_in[8];
    const float* hW1   = (const float*)d_in[9];
    const float* hb1   = (const float*)d_in[10];
    const float* hW2   = (const float*)d_in[11];
    const float* hb2   = (const float*)d_in[12];
    const float* oW    = (const float*)d_in[13];
    const float* ob    = (const float*)d_in[14];
    float* out = (float*)d_out;

    char* ws = (char*)d_ws;
    size_t off_b = 0;
    auto alloc = [&](size_t bytes) {
        size_t p = (off_b + 255) & ~(size_t)255;
        off_b = p + bytes;
        return p;
    };
    // total ~186 MB (R2-proven budget 254 MB; R3's 262 MB died)
    size_t o_dinv = alloc((size_t)N_NODES * 4);
    size_t o_indeg= alloc((size_t)(N_NODES + 1) * 4);
    size_t o_off  = alloc((size_t)(N_NODES + 1) * 4);
    size_t o_cur  = alloc((size_t)N_NODES * 4);
    size_t o_csrc = alloc((size_t)N_TOT_E * 4);
    size_t o_cnrm = alloc((size_t)N_TOT_E * 4);
    size_t o_xf   = alloc((size_t)N_NODES * IN_GNN * 4);
    size_t o_aggh = alloc((size_t)N_NODES * K1PAD * 2);  // bf16 hi, padded
    size_t o_aggl = alloc((size_t)N_NODES * K1PAD * 2);  // bf16 lo
    size_t o_w1h  = alloc((size_t)H1 * K1PAD * 2);       // W1^T hi bf16 [2048][64]
    size_t o_w1l  = alloc((size_t)H1 * K1PAD * 2);
    size_t o_x1h  = alloc((size_t)CHUNK0 * H1 * 2);      // chunk-local bf16 hi
    size_t o_x1l  = alloc((size_t)CHUNK0 * H1 * 2);      // chunk-local bf16 lo
    size_t o_w2h  = alloc((size_t)H2 * H1 * 2);          // W2^T hi bf16 [1024][2048]
    size_t o_w2l  = alloc((size_t)H2 * H1 * 2);
    size_t o_xw2  = alloc((size_t)N_NODES * H2 * 4);
    size_t o_pool = alloc((size_t)N_GRAPHS * H2 * 4);
    size_t o_cnt  = alloc((size_t)N_GRAPHS * 4);
    size_t o_h1   = alloc((size_t)N_GRAPHS * 1024 * 4);
    size_t o_h2   = alloc((size_t)N_GRAPHS * 512 * 4);

    float* dinv = (float*)(ws + o_dinv);
    int*   indeg= (int*)(ws + o_indeg);
    int*   offs = (int*)(ws + o_off);
    int*   cur  = (int*)(ws + o_cur);
    int*   csrc = (int*)(ws + o_csrc);
    float* cnrm = (float*)(ws + o_cnrm);
    float* xf   = (float*)(ws + o_xf);
    u16*   aggh = (u16*)(ws + o_aggh);
    u16*   aggl = (u16*)(ws + o_aggl);
    u16*   w1h  = (u16*)(ws + o_w1h);
    u16*   w1l  = (u16*)(ws + o_w1l);
    u16*   x1h  = (u16*)(ws + o_x1h);
    u16*   x1l  = (u16*)(ws + o_x1l);
    u16*   w2h  = (u16*)(ws + o_w2h);
    u16*   w2l  = (u16*)(ws + o_w2l);
    float* xw2  = (float*)(ws + o_xw2);
    // x2 aliases the x1h+x1l region (82.8 MB contiguous >= 80 MB; both dead then)
    float* x2   = (float*)(ws + o_x1h);
    float* pooled = (float*)(ws + o_pool);
    float* cnt  = (float*)(ws + o_cnt);
    float* h1   = (float*)(ws + o_h1);
    float* h2   = (float*)(ws + o_h2);

    // indegree (int); self loop = init 1; dinv = rsqrt(deg)
    fill_i32<<<(N_NODES + 255) / 256, 256, 0, stream>>>(indeg, 1, N_NODES);
    deg_accum<<<(N_EDGES + 255) / 256, 256, 0, stream>>>(ei, indeg);
    deg_to_dinv<<<(N_NODES + 255) / 256, 256, 0, stream>>>(indeg, dinv);

    // CSR
    scan_offsets<<<1, 1024, 0, stream>>>(indeg, offs, cur);
    csr_fill<<<(N_TOT_E + 255) / 256, 256, 0, stream>>>(ei, dinv, cur, csrc, cnrm);

    // node features + layer-1 aggregation (full graph) -> padded hi/lo bf16
    build_xfeat<<<(N_NODES * IN_GNN + 255) / 256, 256, 0, stream>>>(ids, other, emb, xf);
    agg_csr_36<<<(N_NODES * K1PAD + 255) / 256, 256, 0, stream>>>(offs, csrc, cnrm, xf, aggh, aggl);

    // weights -> transposed hi/lo bf16 (once)
    conv_w1<<<(H1 * K1PAD + 255) / 256, 256, 0, stream>>>(W1, w1h, w1l);
    conv_w2<<<dim3(H1 / 32, H2 / 32), 256, 0, stream>>>(W2, w2h, w2l);

    // layers 1+2 GEMMs in two M-chunks to bound workspace
    {
        const int c0 = CHUNK0, c1 = N_NODES - CHUNK0;   // 10112, 9888
        // chunk 0: gemm2 grid 8 x 79 = 632 (% 8 == 0)
        gemm1_mfma<<<dim3(H1 / 128, c0 / 128), 256, 0, stream>>>(aggh, aggl, w1h, w1l, b1, x1h, x1l, 0, c0);
        gemm2_mfma<<<dim3(H2 / 128, c0 / 128), 256, 0, stream>>>(x1h, x1l, w2h, w2l, xw2, 0, c0);
        // chunk 1: grid 8 x 78 = 624 (% 8 == 0)
        gemm1_mfma<<<dim3(H1 / 128, (c1 + 127) / 128), 256, 0, stream>>>(aggh, aggl, w1h, w1l, b1, x1h, x1l, c0, c1);
        gemm2_mfma<<<dim3(H2 / 128, (c1 + 127) / 128), 256, 0, stream>>>(x1h, x1l, w2h, w2l, xw2, c0, c1);
    }

    // layer-2 aggregation with bias+relu fused (x2 overwrites dead x1h/x1l region)
    agg_csr_1024<<<N_NODES, 256, 0, stream>>>(offs, csrc, cnrm, xw2, b2, x2);

    // mean pool
    hipMemsetAsync(pooled, 0, (size_t)N_GRAPHS * H2 * 4, stream);
    hipMemsetAsync(cnt, 0, (size_t)N_GRAPHS * 4, stream);
    cnt_accum<<<(N_NODES + 255) / 256, 256, 0, stream>>>(batch, cnt);
    pool_accum<<<dim3(H2 / 256, (N_NODES + 63) / 64), 256, 0, stream>>>(batch, x2, pooled);
    pool_norm<<<(N_GRAPHS * H2 + 255) / 256, 256, 0, stream>>>(pooled, cnt);

    // head: fused non-atomic GEMMs
    head_fused<<<dim3(1024 / 256, N_GRAPHS / 8), 256, 0, stream>>>(pooled, hW1, hb1, h1, 1024, 1024, 1);
    head_fused<<<dim3(512 / 256, N_GRAPHS / 8), 256, 0, stream>>>(h1, hW2, hb2, h2, 1024, 512, 1);
    head3<<<1, 128, 0, stream>>>(h2, oW, ob, out);
}

// Round 10
// 886.077 us; speedup vs baseline: 1.4100x; 1.1933x over previous
//
#include <hip/hip_runtime.h>
#include <hip/hip_bf16.h>

#define N_NODES  20000
#define N_EDGES  160000
#define N_TOT_E  180000   // edges + self loops
#define N_GRAPHS 64
#define EMBED_DIM 32
#define IN_GNN   36
#define K1PAD    64       // gemm1 K padded for MFMA
#define H1       2048
#define H2       1024
#define CHUNK0   10112    // 79 * 128; chunk1 = 9888 = N_NODES - CHUNK0

typedef unsigned short u16;
typedef short bf16x8 __attribute__((ext_vector_type(8)));
typedef float f32x4  __attribute__((ext_vector_type(4)));
typedef u16   u16x8  __attribute__((ext_vector_type(8)));

__device__ inline u16 f32_to_bf16(float f) {
    union { float f; unsigned u; } v; v.f = f;
    unsigned lsb = (v.u >> 16) & 1u;
    return (u16)((v.u + 0x7fffu + lsb) >> 16);
}
__device__ inline float bf16_to_f32(u16 h) {
    union { unsigned u; float f; } v; v.u = ((unsigned)h) << 16;
    return v.f;
}

// ---------------- small utility kernels ----------------

__global__ void fill_i32(int* p, int v, int n) {
    int i = blockIdx.x * 256 + threadIdx.x;
    if (i < n) p[i] = v;
}

__global__ void deg_accum(const int* __restrict__ ei, int* indeg) {
    int e = blockIdx.x * 256 + threadIdx.x;
    if (e < N_EDGES) atomicAdd(&indeg[ei[N_EDGES + e]], 1);
}

__global__ void deg_to_dinv(const int* __restrict__ indeg, float* __restrict__ d) {
    int i = blockIdx.x * 256 + threadIdx.x;
    if (i < N_NODES) d[i] = rsqrtf((float)indeg[i]);   // deg >= 1 (self loop)
}

__global__ void build_xfeat(const int* __restrict__ ids, const float* __restrict__ other,
                            const float* __restrict__ emb, float* __restrict__ xf) {
    int idx = blockIdx.x * 256 + threadIdx.x;   // node*36 + d
    if (idx >= N_NODES * IN_GNN) return;
    int i = idx / IN_GNN;
    int d = idx - i * IN_GNN;
    float v = (d < EMBED_DIM) ? emb[(size_t)ids[i] * EMBED_DIM + d]
                              : other[i * 4 + (d - EMBED_DIM)];
    xf[idx] = v;
}

// ---------------- CSR build (R6-proven barrier scan) ----------------
__global__ __launch_bounds__(1024) void scan_offsets(const int* __restrict__ indeg,
                                                     int* __restrict__ off,
                                                     int* __restrict__ cursor) {
    __shared__ int buf[1024];
    __shared__ int base_s;
    int tid = threadIdx.x;
    if (tid == 0) base_s = 0;
    __syncthreads();
    for (int start = 0; start < N_NODES; start += 1024) {
        int i = start + tid;
        int v = (i < N_NODES) ? indeg[i] : 0;
        buf[tid] = v;
        __syncthreads();
        for (int s = 1; s < 1024; s <<= 1) {
            int t = (tid >= s) ? buf[tid - s] : 0;
            __syncthreads();
            buf[tid] += t;
            __syncthreads();
        }
        int incl = buf[tid];
        int excl = incl - v;
        int base = base_s;
        if (i < N_NODES) {
            int o = base + excl;
            off[i] = o;
            cursor[i] = o;
        }
        __syncthreads();
        if (tid == 1023) base_s = base + incl;
        __syncthreads();
    }
    if (tid == 0) off[N_NODES] = N_TOT_E;
}

__global__ void csr_fill(const int* __restrict__ ei, const float* __restrict__ dinv,
                         int* __restrict__ cursor,
                         int* __restrict__ csr_src, float* __restrict__ csr_nrm) {
    int e = blockIdx.x * 256 + threadIdx.x;
    if (e >= N_TOT_E) return;
    int s, t;
    if (e < N_EDGES) { s = ei[e]; t = ei[N_EDGES + e]; }
    else             { s = t = e - N_EDGES; }
    int pos = atomicAdd(&cursor[t], 1);
    csr_src[pos] = s;
    csr_nrm[pos] = dinv[s] * dinv[t];
}

// ---------------- layer-1 aggregation via CSR gather -> hi/lo bf16, [node][64] padded
__global__ void agg_csr_36(const int* __restrict__ off, const int* __restrict__ csr_src,
                           const float* __restrict__ csr_nrm,
                           const float* __restrict__ xf,
                           u16* __restrict__ aggh, u16* __restrict__ aggl) {
    int idx = blockIdx.x * 256 + threadIdx.x;   // node*64 + d
    if (idx >= N_NODES * K1PAD) return;
    int node = idx >> 6;
    int d = idx & 63;
    u16 hi = 0, lo = 0;
    if (d < IN_GNN) {
        int p0 = off[node], p1 = off[node + 1];
        float acc = 0.0f;
        for (int p = p0; p < p1; p++)
            acc += xf[csr_src[p] * IN_GNN + d] * csr_nrm[p];
        hi = f32_to_bf16(acc);
        lo = f32_to_bf16(acc - bf16_to_f32(hi));
    }
    aggh[idx] = hi;
    aggl[idx] = lo;
}

// ---------------- W1 [36,2048] f32 -> transposed hi/lo bf16 [2048][64] (padded) ----
__global__ void conv_w1(const float* __restrict__ W,
                        u16* __restrict__ Bh, u16* __restrict__ Bl) {
    int idx = blockIdx.x * 256 + threadIdx.x;   // n*64 + k
    if (idx >= H1 * K1PAD) return;
    int n = idx >> 6;
    int k = idx & 63;
    u16 hi = 0, lo = 0;
    if (k < IN_GNN) {
        float v = W[(size_t)k * H1 + n];
        hi = f32_to_bf16(v);
        lo = f32_to_bf16(v - bf16_to_f32(hi));
    }
    Bh[idx] = hi;
    Bl[idx] = lo;
}

// ---------------- W2 [2048,1024] f32 -> transposed hi/lo bf16 [1024,2048] ----------
__global__ __launch_bounds__(256) void conv_w2(const float* __restrict__ W,
                                               u16* __restrict__ Bh,
                                               u16* __restrict__ Bl) {
    __shared__ float t[32][33];
    int bk = blockIdx.x * 32;   // k block
    int bn = blockIdx.y * 32;   // n block
    int tx = threadIdx.x & 31, ty = threadIdx.x >> 5;   // 32 x 8
#pragma unroll
    for (int i = 0; i < 32; i += 8)
        t[ty + i][tx] = W[(size_t)(bk + ty + i) * H2 + bn + tx];
    __syncthreads();
#pragma unroll
    for (int i = 0; i < 32; i += 8) {
        float v = t[tx][ty + i];            // = W[bk+tx][bn+ty+i]
        u16 hi = f32_to_bf16(v);
        u16 lo = f32_to_bf16(v - bf16_to_f32(hi));
        size_t o = (size_t)(bn + ty + i) * H1 + bk + tx;   // Bt[n][k]
        Bh[o] = hi;
        Bl[o] = lo;
    }
}

// ---------------- GEMM1 via bf16 MFMA: agg[rows,64p] @ W1t[2048,64p] + b1, relu ----
// Epilogue now LDS-staged: frag f32 -> LDS (exact 64KB reuse) -> coalesced 16B
// hi/lo vector stores (was 128 scalar 2B scattered stores/thread).
__global__ __launch_bounds__(256) void gemm1_mfma(const u16* __restrict__ Ah,
                                                  const u16* __restrict__ Al,
                                                  const u16* __restrict__ Bh,
                                                  const u16* __restrict__ Bl,
                                                  const float* __restrict__ bias,
                                                  u16* __restrict__ Xh,
                                                  u16* __restrict__ Xl,
                                                  int rowbase, int nrows) {
    __shared__ __align__(16) u16 lds[4][128 * K1PAD];   // 16 KB each, 64 KB total
    const int tid  = threadIdx.x;
    const int wid  = tid >> 6;
    const int lane = tid & 63;
    const int wr   = wid >> 1, wc = wid & 1;
    const int row0 = blockIdx.y * 128;          // chunk-local
    const int col0 = blockIdx.x * 128;          // over H1=2048

    const u16* gbase;
    int rbase; bool isA;
    if      (wid == 0) { gbase = Ah; rbase = row0; isA = true; }
    else if (wid == 1) { gbase = Al; rbase = row0; isA = true; }
    else if (wid == 2) { gbase = Bh; rbase = col0; isA = false; }
    else               { gbase = Bl; rbase = col0; isA = false; }
    u16* myl = lds[wid];
    const int r_l  = lane >> 3;        // 0..7 row within 8-row group
    const int ks_l = (lane & 7) * 8;   // k offset
#pragma unroll
    for (int i = 0; i < 16; i++) {
        int r = rbase + i * 8 + r_l;
        if (isA) { int g = rowbase + ((r > nrows - 1) ? (nrows - 1) : r);
                   r = g; }
        const u16* g = gbase + (size_t)r * K1PAD + ks_l;
        __builtin_amdgcn_global_load_lds(
            (const __attribute__((address_space(1))) void*)g,
            (__attribute__((address_space(3))) void*)(myl + i * 512),
            16, 0, 0);
    }
    __syncthreads();   // drains vmcnt; all 4 tiles visible

    f32x4 acc[4][4] = {};
#pragma unroll
    for (int ks = 0; ks < 2; ks++) {
        bf16x8 afh[4], afl[4];
#pragma unroll
        for (int mi = 0; mi < 4; mi++) {
            int r   = wr * 64 + mi * 16 + (lane & 15);
            int off = r * K1PAD + ks * 32 + (lane >> 4) * 8;
            afh[mi] = *(const bf16x8*)&lds[0][off];
            afl[mi] = *(const bf16x8*)&lds[1][off];
        }
#pragma unroll
        for (int ni = 0; ni < 4; ni++) {
            int c   = wc * 64 + ni * 16 + (lane & 15);
            int off = c * K1PAD + ks * 32 + (lane >> 4) * 8;
            bf16x8 bfh = *(const bf16x8*)&lds[2][off];
            bf16x8 bfl = *(const bf16x8*)&lds[3][off];
#pragma unroll
            for (int mi = 0; mi < 4; mi++) {
                acc[mi][ni] = __builtin_amdgcn_mfma_f32_16x16x32_bf16(afh[mi], bfh, acc[mi][ni], 0, 0, 0);
                acc[mi][ni] = __builtin_amdgcn_mfma_f32_16x16x32_bf16(afh[mi], bfl, acc[mi][ni], 0, 0, 0);
                acc[mi][ni] = __builtin_amdgcn_mfma_f32_16x16x32_bf16(afl[mi], bfh, acc[mi][ni], 0, 0, 0);
            }
        }
    }

    // ---- epilogue: bias+relu into LDS f32[128][128] (exact 64KB), then coalesced stores
    __syncthreads();   // all waves finished reading staged operands from LDS
    float (*ldsF)[128] = (float (*)[128])(&lds[0][0]);
#pragma unroll
    for (int ni = 0; ni < 4; ni++) {
        int colL = wc * 64 + ni * 16 + (lane & 15);
        float bb = bias[col0 + colL];
#pragma unroll
        for (int mi = 0; mi < 4; mi++) {
#pragma unroll
            for (int j = 0; j < 4; j++) {
                int rowL = wr * 64 + mi * 16 + (lane >> 4) * 4 + j;
                ldsF[rowL][colL] = fmaxf(acc[mi][ni][j] + bb, 0.0f);
            }
        }
    }
    __syncthreads();
    int rL = tid >> 1;                 // 0..127 block-local row
    int cb = (tid & 1) * 8;            // interleaved 16B chunks within the row
    int lr = row0 + rL;
    if (lr < nrows) {
        size_t gb = (size_t)lr * H1 + col0;
#pragma unroll
        for (int c = 0; c < 8; c++) {
            int col = c * 16 + cb;     // 8 consecutive u16 = 16 B
            u16x8 hv, lv;
#pragma unroll
            for (int e = 0; e < 8; e++) {
                float v = ldsF[rL][col + e];
                u16 h = f32_to_bf16(v);
                hv[e] = h;
                lv[e] = f32_to_bf16(v - bf16_to_f32(h));
            }
            *(u16x8*)&Xh[gb + col] = hv;
            *(u16x8*)&Xl[gb + col] = lv;
        }
    }
}

// ---------------- GEMM2 via bf16 MFMA (hi/lo split, 3 products) -----------------
// R6-proven: 128x128 tile, BK=32, 4 waves. XCD remap keeps one A row-panel per XCD.
// (R7's 128x64 tile regressed: staging bytes/MFMA doubled -> MfmaUtil 38->25%.)
__global__ __launch_bounds__(256) void gemm2_mfma(const u16* __restrict__ Ah,
                                                  const u16* __restrict__ Al,
                                                  const u16* __restrict__ Bh,
                                                  const u16* __restrict__ Bl,
                                                  float* __restrict__ C,
                                                  int rowbase, int nrows) {
    __shared__ u16 lds[4][128 * 32];   // Ah, Al, Bh, Bl tiles: 8 KB each
    const int tid  = threadIdx.x;
    const int wid  = tid >> 6;
    const int lane = tid & 63;
    const int wr   = wid >> 1, wc = wid & 1;

    // ---- XCD-aware bijective remap (grid NB % 8 == 0) ----
    int NB = (int)(gridDim.x * gridDim.y);
    int b  = (int)(blockIdx.y * gridDim.x + blockIdx.x);
    int lin = b;
    if ((NB & 7) == 0) {
        int xcd = b & 7, j = b >> 3;      // round-robin slot -> contiguous run
        lin = xcd * (NB >> 3) + j;
    }
    const int col0 = (lin & 7) * 128;
    const int row0 = (lin >> 3) * 128;    // chunk-local

    const u16* gbase;
    int rbase;
    if      (wid == 0) { gbase = Ah; rbase = row0; }
    else if (wid == 1) { gbase = Al; rbase = row0; }
    else if (wid == 2) { gbase = Bh; rbase = col0; }
    else               { gbase = Bl; rbase = col0; }
    u16* myl = lds[wid];
    const int r_l  = lane >> 2;        // 0..15
    const int ks_l = (lane & 3) * 8;   // 0,8,16,24  (lds dest byte = lane*16, linear)

    int rows[8];
#pragma unroll
    for (int i = 0; i < 8; i++) {
        int r = rbase + i * 16 + r_l;
        if (wid < 2 && r > nrows - 1) r = nrows - 1;   // clamp A-side reads to chunk
        rows[i] = r;
    }

    f32x4 acc[4][4] = {};

    for (int kt = 0; kt < H1 / 32; ++kt) {
        int k0 = kt * 32;
        __syncthreads();   // previous compute done before overwrite
#pragma unroll
        for (int i = 0; i < 8; i++) {
            const u16* g = gbase + (size_t)rows[i] * H1 + k0 + ks_l;
            __builtin_amdgcn_global_load_lds(
                (const __attribute__((address_space(1))) void*)g,
                (__attribute__((address_space(3))) void*)(myl + i * 512),
                16, 0, 0);
        }
        __syncthreads();   // compiler drains vmcnt before barrier

        bf16x8 afh[4], afl[4];
#pragma unroll
        for (int mi = 0; mi < 4; mi++) {
            int r   = wr * 64 + mi * 16 + (lane & 15);
            int off = r * 32 + (lane >> 4) * 8;
            afh[mi] = *(const bf16x8*)&lds[0][off];
            afl[mi] = *(const bf16x8*)&lds[1][off];
        }
#pragma unroll
        for (int ni = 0; ni < 4; ni++) {
            int c   = wc * 64 + ni * 16 + (lane & 15);
            int off = c * 32 + (lane >> 4) * 8;
            bf16x8 bfh = *(const bf16x8*)&lds[2][off];
            bf16x8 bfl = *(const bf16x8*)&lds[3][off];
#pragma unroll
            for (int mi = 0; mi < 4; mi++) {
                acc[mi][ni] = __builtin_amdgcn_mfma_f32_16x16x32_bf16(afh[mi], bfh, acc[mi][ni], 0, 0, 0);
                acc[mi][ni] = __builtin_amdgcn_mfma_f32_16x16x32_bf16(afh[mi], bfl, acc[mi][ni], 0, 0, 0);
                acc[mi][ni] = __builtin_amdgcn_mfma_f32_16x16x32_bf16(afl[mi], bfh, acc[mi][ni], 0, 0, 0);
            }
        }
    }

    // C/D layout: col = lane&15, row = (lane>>4)*4 + j  [m89/m91 verified]
#pragma unroll
    for (int mi = 0; mi < 4; mi++) {
#pragma unroll
        for (int ni = 0; ni < 4; ni++) {
            int col = col0 + wc * 64 + ni * 16 + (lane & 15);
#pragma unroll
            for (int j = 0; j < 4; j++) {
                int lr = row0 + wr * 64 + mi * 16 + (lane >> 4) * 4 + j;
                if (lr < nrows) C[(size_t)(rowbase + lr) * H2 + col] = acc[mi][ni][j];
            }
        }
    }
}

// ---------------- layer-2 aggregation via CSR gather (1024-dim), bias+relu fused ----
__global__ __launch_bounds__(256) void agg_csr_1024(const int* __restrict__ off,
                                                    const int* __restrict__ csr_src,
                                                    const float* __restrict__ csr_nrm,
                                                    const float* __restrict__ xw,
                                                    const float* __restrict__ b,
                                                    float* __restrict__ x2) {
    int node = blockIdx.x;
    int p0 = off[node], p1 = off[node + 1];
    int d = threadIdx.x;             // float4 lane: 256 x 4 = 1024 dims
    float4 a0 = make_float4(0.f, 0.f, 0.f, 0.f);
    float4 a1 = make_float4(0.f, 0.f, 0.f, 0.f);
    int p = p0;
    for (; p + 1 < p1; p += 2) {
        int   s0 = csr_src[p],     s1 = csr_src[p + 1];
        float n0 = csr_nrm[p],     n1 = csr_nrm[p + 1];
        float4 v0 = ((const float4*)&xw[(size_t)s0 * H2])[d];
        float4 v1 = ((const float4*)&xw[(size_t)s1 * H2])[d];
        a0.x += v0.x * n0; a0.y += v0.y * n0; a0.z += v0.z * n0; a0.w += v0.w * n0;
        a1.x += v1.x * n1; a1.y += v1.y * n1; a1.z += v1.z * n1; a1.w += v1.w * n1;
    }
    if (p < p1) {
        int   s0 = csr_src[p];
        float n0 = csr_nrm[p];
        float4 v0 = ((const float4*)&xw[(size_t)s0 * H2])[d];
        a0.x += v0.x * n0; a0.y += v0.y * n0; a0.z += v0.z * n0; a0.w += v0.w * n0;
    }
    float4 bb = ((const float4*)b)[d];
    float4 o;
    o.x = fmaxf(a0.x + a1.x + bb.x, 0.f);
    o.y = fmaxf(a0.y + a1.y + bb.y, 0.f);
    o.z = fmaxf(a0.z + a1.z + bb.z, 0.f);
    o.w = fmaxf(a0.w + a1.w + bb.w, 0.f);
    ((float4*)&x2[(size_t)node * H2])[d] = o;
}

// ---------------- pooling ----------------
__global__ void cnt_accum(const int* __restrict__ batch, float* cnt) {
    int i = blockIdx.x * 256 + threadIdx.x;
    if (i < N_NODES) atomicAdd(&cnt[batch[i]], 1.0f);
}

__global__ void pool_accum(const int* __restrict__ batch, const float* __restrict__ x2,
                           float* __restrict__ pooled) {
    int d  = blockIdx.x * 256 + threadIdx.x;   // 0..1023
    int i0 = blockIdx.y * 64;
    float acc = 0.0f;
    int gprev = -1;
    for (int i = 0; i < 64; i++) {
        int node = i0 + i;
        if (node >= N_NODES) break;
        int g = batch[node];
        if (g != gprev) {
            if (gprev >= 0) atomicAdd(&pooled[gprev * H2 + d], acc);
            acc = 0.0f; gprev = g;
        }
        acc += x2[(size_t)node * H2 + d];
    }
    if (gprev >= 0) atomicAdd(&pooled[gprev * H2 + d], acc);
}

__global__ void pool_norm(float* pooled, const float* cnt) {
    int idx = blockIdx.x * 256 + threadIdx.x;
    if (idx < N_GRAPHS * H2) {
        int g = idx >> 10;
        pooled[idx] /= fmaxf(cnt[g], 1.0f);
    }
}

// ---------------- MLP head (R6-proven k-split atomic version) ----------------
__global__ __launch_bounds__(256) void head_gemm(const float* __restrict__ In,
                                                 const float* __restrict__ W,
                                                 float* __restrict__ Out, int K, int N) {
    __shared__ __align__(16) float As[16][256];
    int n  = blockIdx.x * 256 + threadIdx.x;
    int m0 = blockIdx.y * 16;
    int k0 = blockIdx.z * 256;
    for (int t = threadIdx.x; t < 16 * 256; t += 256) {
        int r = t >> 8, k = t & 255;
        As[r][k] = In[(size_t)(m0 + r) * K + k0 + k];
    }
    __syncthreads();
    float acc[16] = {};
    for (int k = 0; k < 256; k += 4) {
        float w0 = W[(size_t)(k0 + k + 0) * N + n];
        float w1 = W[(size_t)(k0 + k + 1) * N + n];
        float w2 = W[(size_t)(k0 + k + 2) * N + n];
        float w3 = W[(size_t)(k0 + k + 3) * N + n];
#pragma unroll
        for (int r = 0; r < 16; r++) {
            float4 a = *(const float4*)&As[r][k];
            acc[r] += a.x * w0 + a.y * w1 + a.z * w2 + a.w * w3;
        }
    }
    for (int r = 0; r < 16; r++)
        atomicAdd(&Out[(size_t)(m0 + r) * N + n], acc[r]);
}

__global__ void bias_relu_MN(float* __restrict__ x, const float* __restrict__ b,
                             int N, int total) {
    int idx = blockIdx.x * 256 + threadIdx.x;
    if (idx < total) {
        int d = idx & (N - 1);    // N is a power of two
        x[idx] = fmaxf(x[idx] + b[d], 0.0f);
    }
}

__global__ void head3(const float* __restrict__ h2, const float* __restrict__ oW,
                      const float* __restrict__ ob, float* __restrict__ out) {
    int tid = threadIdx.x;          // 128 threads: m = tid/2, c = tid&1
    if (tid >= 128) return;
    int m = tid >> 1, c = tid & 1;
    float acc = 0.0f;
    for (int k = 0; k < 512; k++) acc += h2[m * 512 + k] * oW[k * 2 + c];
    out[tid] = acc + ob[c];
}

// ---------------- host ----------------
extern "C" void kernel_launch(void* const* d_in, const int* in_sizes, int n_in,
                              void* d_out, int out_size, void* d_ws, size_t ws_size,
                              hipStream_t stream) {
    const int*   ids   = (const int*)d_in[0];
    const float* other = (const float*)d_in[1];
    const int*   ei    = (const int*)d_in[2];
    const int*   batch = (const int*)d_in[3];
    const float* emb   = (const float*)d_in[4];
    const float* W1    = (const float*)d_in[5];
    const float* b1    = (const float*)d_in[6];
    const float* W2    = (const float*)d_in[7];
    const float* b2    = (const float*)d_in[8];
    const float* hW1   = (const float*)d_in[9];
    const float* hb1   = (const float*)d_in[10];
    const float* hW2   = (const float*)d_in[11];
    const float* hb2   = (const float*)d_in[12];
    const float* oW    = (const float*)d_in[13];
    const float* ob    = (const float*)d_in[14];
    float* out = (float*)d_out;

    char* ws = (char*)d_ws;
    size_t off_b = 0;
    auto alloc = [&](size_t bytes) {
        size_t p = (off_b + 255) & ~(size_t)255;
        off_b = p + bytes;
        return p;
    };
    // total ~186 MB (R2-proven budget 254 MB; R3's 262 MB died)
    size_t o_dinv = alloc((size_t)N_NODES * 4);
    size_t o_indeg= alloc((size_t)(N_NODES + 1) * 4);
    size_t o_off  = alloc((size_t)(N_NODES + 1) * 4);
    size_t o_cur  = alloc((size_t)N_NODES * 4);
    size_t o_csrc = alloc((size_t)N_TOT_E * 4);
    size_t o_cnrm = alloc((size_t)N_TOT_E * 4);
    size_t o_xf   = alloc((size_t)N_NODES * IN_GNN * 4);
    size_t o_aggh = alloc((size_t)N_NODES * K1PAD * 2);  // bf16 hi, padded
    size_t o_aggl = alloc((size_t)N_NODES * K1PAD * 2);  // bf16 lo
    size_t o_w1h  = alloc((size_t)H1 * K1PAD * 2);       // W1^T hi bf16 [2048][64]
    size_t o_w1l  = alloc((size_t)H1 * K1PAD * 2);
    size_t o_x1h  = alloc((size_t)CHUNK0 * H1 * 2);      // chunk-local bf16 hi
    size_t o_x1l  = alloc((size_t)CHUNK0 * H1 * 2);      // chunk-local bf16 lo
    size_t o_w2h  = alloc((size_t)H2 * H1 * 2);          // W2^T hi bf16 [1024][2048]
    size_t o_w2l  = alloc((size_t)H2 * H1 * 2);
    size_t o_xw2  = alloc((size_t)N_NODES * H2 * 4);
    size_t o_pool = alloc((size_t)N_GRAPHS * H2 * 4);
    size_t o_cnt  = alloc((size_t)N_GRAPHS * 4);
    size_t o_h1   = alloc((size_t)N_GRAPHS * 1024 * 4);
    size_t o_h2   = alloc((size_t)N_GRAPHS * 512 * 4);

    float* dinv = (float*)(ws + o_dinv);
    int*   indeg= (int*)(ws + o_indeg);
    int*   offs = (int*)(ws + o_off);
    int*   cur  = (int*)(ws + o_cur);
    int*   csrc = (int*)(ws + o_csrc);
    float* cnrm = (float*)(ws + o_cnrm);
    float* xf   = (float*)(ws + o_xf);
    u16*   aggh = (u16*)(ws + o_aggh);
    u16*   aggl = (u16*)(ws + o_aggl);
    u16*   w1h  = (u16*)(ws + o_w1h);
    u16*   w1l  = (u16*)(ws + o_w1l);
    u16*   x1h  = (u16*)(ws + o_x1h);
    u16*   x1l  = (u16*)(ws + o_x1l);
    u16*   w2h  = (u16*)(ws + o_w2h);
    u16*   w2l  = (u16*)(ws + o_w2l);
    float* xw2  = (float*)(ws + o_xw2);
    // x2 aliases the x1h+x1l region (82.8 MB contiguous >= 80 MB; both dead then)
    float* x2   = (float*)(ws + o_x1h);
    float* pooled = (float*)(ws + o_pool);
    float* cnt  = (float*)(ws + o_cnt);
    float* h1   = (float*)(ws + o_h1);
    float* h2   = (float*)(ws + o_h2);

    // indegree (int); self loop = init 1; dinv = rsqrt(deg)
    fill_i32<<<(N_NODES + 255) / 256, 256, 0, stream>>>(indeg, 1, N_NODES);
    deg_accum<<<(N_EDGES + 255) / 256, 256, 0, stream>>>(ei, indeg);
    deg_to_dinv<<<(N_NODES + 255) / 256, 256, 0, stream>>>(indeg, dinv);

    // CSR
    scan_offsets<<<1, 1024, 0, stream>>>(indeg, offs, cur);
    csr_fill<<<(N_TOT_E + 255) / 256, 256, 0, stream>>>(ei, dinv, cur, csrc, cnrm);

    // node features + layer-1 aggregation (full graph) -> padded hi/lo bf16
    build_xfeat<<<(N_NODES * IN_GNN + 255) / 256, 256, 0, stream>>>(ids, other, emb, xf);
    agg_csr_36<<<(N_NODES * K1PAD + 255) / 256, 256, 0, stream>>>(offs, csrc, cnrm, xf, aggh, aggl);

    // weights -> transposed hi/lo bf16 (once)
    conv_w1<<<(H1 * K1PAD + 255) / 256, 256, 0, stream>>>(W1, w1h, w1l);
    conv_w2<<<dim3(H1 / 32, H2 / 32), 256, 0, stream>>>(W2, w2h, w2l);

    // layers 1+2 GEMMs in two M-chunks to bound workspace
    {
        const int c0 = CHUNK0, c1 = N_NODES - CHUNK0;   // 10112, 9888
        // chunk 0: gemm2 grid 8 x 79 = 632 (% 8 == 0)
        gemm1_mfma<<<dim3(H1 / 128, c0 / 128), 256, 0, stream>>>(aggh, aggl, w1h, w1l, b1, x1h, x1l, 0, c0);
        gemm2_mfma<<<dim3(H2 / 128, c0 / 128), 256, 0, stream>>>(x1h, x1l, w2h, w2l, xw2, 0, c0);
        // chunk 1: grid 8 x 78 = 624 (% 8 == 0)
        gemm1_mfma<<<dim3(H1 / 128, (c1 + 127) / 128), 256, 0, stream>>>(aggh, aggl, w1h, w1l, b1, x1h, x1l, c0, c1);
        gemm2_mfma<<<dim3(H2 / 128, (c1 + 127) / 128), 256, 0, stream>>>(x1h, x1l, w2h, w2l, xw2, c0, c1);
    }

    // layer-2 aggregation with bias+relu fused (x2 overwrites dead x1h/x1l region)
    agg_csr_1024<<<N_NODES, 256, 0, stream>>>(offs, csrc, cnrm, xw2, b2, x2);

    // mean pool
    hipMemsetAsync(pooled, 0, (size_t)N_GRAPHS * H2 * 4, stream);
    hipMemsetAsync(cnt, 0, (size_t)N_GRAPHS * 4, stream);
    cnt_accum<<<(N_NODES + 255) / 256, 256, 0, stream>>>(batch, cnt);
    pool_accum<<<dim3(H2 / 256, (N_NODES + 63) / 64), 256, 0, stream>>>(batch, x2, pooled);
    pool_norm<<<(N_GRAPHS * H2 + 255) / 256, 256, 0, stream>>>(pooled, cnt);

    // head (R6-proven)
    hipMemsetAsync(h1, 0, (size_t)N_GRAPHS * 1024 * 4, stream);
    head_gemm<<<dim3(1024 / 256, 4, 1024 / 256), 256, 0, stream>>>(pooled, hW1, h1, 1024, 1024);
    bias_relu_MN<<<(N_GRAPHS * 1024 + 255) / 256, 256, 0, stream>>>(h1, hb1, 1024, N_GRAPHS * 1024);

    hipMemsetAsync(h2, 0, (size_t)N_GRAPHS * 512 * 4, stream);
    head_gemm<<<dim3(512 / 256, 4, 1024 / 256), 256, 0, stream>>>(h1, hW2, h2, 1024, 512);
    bias_relu_MN<<<(N_GRAPHS * 512 + 255) / 256, 256, 0, stream>>>(h2, hb2, 512, N_GRAPHS * 512);

    head3<<<1, 128, 0, stream>>>(h2, oW, ob, out);
}

// Round 12
// 839.310 us; speedup vs baseline: 1.4886x; 1.0557x over previous
//
#include <hip/hip_runtime.h>
#include <hip/hip_bf16.h>

#define N_NODES  20000
#define N_EDGES  160000
#define N_TOT_E  180000   // edges + self loops
#define N_GRAPHS 64
#define EMBED_DIM 32
#define IN_GNN   36
#define K1PAD    64       // gemm1 K padded for MFMA
#define H1       2048
#define H2       1024
#define NPANELS  157      // ceil(20000/128)

typedef unsigned short u16;
typedef short bf16x8 __attribute__((ext_vector_type(8)));
typedef float f32x4  __attribute__((ext_vector_type(4)));
typedef _Float16 f16;
typedef f16  f16x8  __attribute__((ext_vector_type(8)));

__device__ inline u16 f32_to_bf16(float f) {
    union { float f; unsigned u; } v; v.f = f;
    unsigned lsb = (v.u >> 16) & 1u;
    return (u16)((v.u + 0x7fffu + lsb) >> 16);
}
__device__ inline float bf16_to_f32(u16 h) {
    union { unsigned u; float f; } v; v.u = ((unsigned)h) << 16;
    return v.f;
}
__device__ inline u16 f16_bits(f16 h) { union { f16 h; u16 u; } v; v.h = h; return v.u; }

// ---------------- small utility kernels ----------------

__global__ void fill_i32(int* p, int v, int n) {
    int i = blockIdx.x * 256 + threadIdx.x;
    if (i < n) p[i] = v;
}

__global__ void deg_accum(const int* __restrict__ ei, int* indeg) {
    int e = blockIdx.x * 256 + threadIdx.x;
    if (e < N_EDGES) atomicAdd(&indeg[ei[N_EDGES + e]], 1);
}

__global__ void deg_to_dinv(const int* __restrict__ indeg, float* __restrict__ d) {
    int i = blockIdx.x * 256 + threadIdx.x;
    if (i < N_NODES) d[i] = rsqrtf((float)indeg[i]);   // deg >= 1 (self loop)
}

__global__ void build_xfeat(const int* __restrict__ ids, const float* __restrict__ other,
                            const float* __restrict__ emb, float* __restrict__ xf) {
    int idx = blockIdx.x * 256 + threadIdx.x;   // node*36 + d
    if (idx >= N_NODES * IN_GNN) return;
    int i = idx / IN_GNN;
    int d = idx - i * IN_GNN;
    float v = (d < EMBED_DIM) ? emb[(size_t)ids[i] * EMBED_DIM + d]
                              : other[i * 4 + (d - EMBED_DIM)];
    xf[idx] = v;
}

// ---------------- CSR build (R6-proven barrier scan) ----------------
__global__ __launch_bounds__(1024) void scan_offsets(const int* __restrict__ indeg,
                                                     int* __restrict__ off,
                                                     int* __restrict__ cursor) {
    __shared__ int buf[1024];
    __shared__ int base_s;
    int tid = threadIdx.x;
    if (tid == 0) base_s = 0;
    __syncthreads();
    for (int start = 0; start < N_NODES; start += 1024) {
        int i = start + tid;
        int v = (i < N_NODES) ? indeg[i] : 0;
        buf[tid] = v;
        __syncthreads();
        for (int s = 1; s < 1024; s <<= 1) {
            int t = (tid >= s) ? buf[tid - s] : 0;
            __syncthreads();
            buf[tid] += t;
            __syncthreads();
        }
        int incl = buf[tid];
        int excl = incl - v;
        int base = base_s;
        if (i < N_NODES) {
            int o = base + excl;
            off[i] = o;
            cursor[i] = o;
        }
        __syncthreads();
        if (tid == 1023) base_s = base + incl;
        __syncthreads();
    }
    if (tid == 0) off[N_NODES] = N_TOT_E;
}

__global__ void csr_fill(const int* __restrict__ ei, const float* __restrict__ dinv,
                         int* __restrict__ cursor,
                         int* __restrict__ csr_src, float* __restrict__ csr_nrm) {
    int e = blockIdx.x * 256 + threadIdx.x;
    if (e >= N_TOT_E) return;
    int s, t;
    if (e < N_EDGES) { s = ei[e]; t = ei[N_EDGES + e]; }
    else             { s = t = e - N_EDGES; }
    int pos = atomicAdd(&cursor[t], 1);
    csr_src[pos] = s;
    csr_nrm[pos] = dinv[s] * dinv[t];
}

// ---------------- layer-1 aggregation via CSR gather -> hi/lo bf16, [node][64] padded
__global__ void agg_csr_36(const int* __restrict__ off, const int* __restrict__ csr_src,
                           const float* __restrict__ csr_nrm,
                           const float* __restrict__ xf,
                           u16* __restrict__ aggh, u16* __restrict__ aggl) {
    int idx = blockIdx.x * 256 + threadIdx.x;   // node*64 + d
    if (idx >= N_NODES * K1PAD) return;
    int node = idx >> 6;
    int d = idx & 63;
    u16 hi = 0, lo = 0;
    if (d < IN_GNN) {
        int p0 = off[node], p1 = off[node + 1];
        float acc = 0.0f;
        for (int p = p0; p < p1; p++)
            acc += xf[csr_src[p] * IN_GNN + d] * csr_nrm[p];
        hi = f32_to_bf16(acc);
        lo = f32_to_bf16(acc - bf16_to_f32(hi));
    }
    aggh[idx] = hi;
    aggl[idx] = lo;
}

// ---------------- W1 [36,2048] f32 -> transposed hi/lo bf16 [2048][64] (padded) ----
__global__ void conv_w1(const float* __restrict__ W,
                        u16* __restrict__ Bh, u16* __restrict__ Bl) {
    int idx = blockIdx.x * 256 + threadIdx.x;   // n*64 + k
    if (idx >= H1 * K1PAD) return;
    int n = idx >> 6;
    int k = idx & 63;
    u16 hi = 0, lo = 0;
    if (k < IN_GNN) {
        float v = W[(size_t)k * H1 + n];
        hi = f32_to_bf16(v);
        lo = f32_to_bf16(v - bf16_to_f32(hi));
    }
    Bh[idx] = hi;
    Bl[idx] = lo;
}

// ---------------- W2 [2048,1024] f32 -> transposed hi/lo FP16 [1024,2048] ----------
__global__ __launch_bounds__(256) void conv_w2(const float* __restrict__ W,
                                               u16* __restrict__ Bh,
                                               u16* __restrict__ Bl) {
    __shared__ float t[32][33];
    int bk = blockIdx.x * 32;   // k block
    int bn = blockIdx.y * 32;   // n block
    int tx = threadIdx.x & 31, ty = threadIdx.x >> 5;   // 32 x 8
#pragma unroll
    for (int i = 0; i < 32; i += 8)
        t[ty + i][tx] = W[(size_t)(bk + ty + i) * H2 + bn + tx];
    __syncthreads();
#pragma unroll
    for (int i = 0; i < 32; i += 8) {
        float v = t[tx][ty + i];            // = W[bk+tx][bn+ty+i]
        f16 h = (f16)v;
        f16 l = (f16)(v - (float)h);
        size_t o = (size_t)(bn + ty + i) * H1 + bk + tx;   // Bt[n][k]
        Bh[o] = f16_bits(h);
        Bl[o] = f16_bits(l);
    }
}

// ---------------- GEMM1 via bf16 MFMA: agg[rows,64p] @ W1t[2048,64p] + b1, relu ----
// Single launch over all nodes. Epilogue: LDS-staged f32, then single FP16 output
// (x1f) via coalesced 16B stores.
__global__ __launch_bounds__(256) void gemm1_mfma(const u16* __restrict__ Ah,
                                                  const u16* __restrict__ Al,
                                                  const u16* __restrict__ Bh,
                                                  const u16* __restrict__ Bl,
                                                  const float* __restrict__ bias,
                                                  u16* __restrict__ Xf) {
    __shared__ __align__(16) u16 lds[4][128 * K1PAD];   // 16 KB each, 64 KB total
    const int tid  = threadIdx.x;
    const int wid  = tid >> 6;
    const int lane = tid & 63;
    const int wr   = wid >> 1, wc = wid & 1;
    const int row0 = blockIdx.y * 128;          // global rows
    const int col0 = blockIdx.x * 128;          // over H1=2048

    const u16* gbase;
    int rbase; bool isA;
    if      (wid == 0) { gbase = Ah; rbase = row0; isA = true; }
    else if (wid == 1) { gbase = Al; rbase = row0; isA = true; }
    else if (wid == 2) { gbase = Bh; rbase = col0; isA = false; }
    else               { gbase = Bl; rbase = col0; isA = false; }
    u16* myl = lds[wid];
    const int r_l  = lane >> 3;        // 0..7 row within 8-row group
    const int ks_l = (lane & 7) * 8;   // k offset
#pragma unroll
    for (int i = 0; i < 16; i++) {
        int r = rbase + i * 8 + r_l;
        if (isA && r > N_NODES - 1) r = N_NODES - 1;
        const u16* g = gbase + (size_t)r * K1PAD + ks_l;
        __builtin_amdgcn_global_load_lds(
            (const __attribute__((address_space(1))) void*)g,
            (__attribute__((address_space(3))) void*)(myl + i * 512),
            16, 0, 0);
    }
    __syncthreads();   // drains vmcnt; all 4 tiles visible

    f32x4 acc[4][4] = {};
#pragma unroll
    for (int ks = 0; ks < 2; ks++) {
        bf16x8 afh[4], afl[4];
#pragma unroll
        for (int mi = 0; mi < 4; mi++) {
            int r   = wr * 64 + mi * 16 + (lane & 15);
            int off = r * K1PAD + ks * 32 + (lane >> 4) * 8;
            afh[mi] = *(const bf16x8*)&lds[0][off];
            afl[mi] = *(const bf16x8*)&lds[1][off];
        }
#pragma unroll
        for (int ni = 0; ni < 4; ni++) {
            int c   = wc * 64 + ni * 16 + (lane & 15);
            int off = c * K1PAD + ks * 32 + (lane >> 4) * 8;
            bf16x8 bfh = *(const bf16x8*)&lds[2][off];
            bf16x8 bfl = *(const bf16x8*)&lds[3][off];
#pragma unroll
            for (int mi = 0; mi < 4; mi++) {
                acc[mi][ni] = __builtin_amdgcn_mfma_f32_16x16x32_bf16(afh[mi], bfh, acc[mi][ni], 0, 0, 0);
                acc[mi][ni] = __builtin_amdgcn_mfma_f32_16x16x32_bf16(afh[mi], bfl, acc[mi][ni], 0, 0, 0);
                acc[mi][ni] = __builtin_amdgcn_mfma_f32_16x16x32_bf16(afl[mi], bfh, acc[mi][ni], 0, 0, 0);
            }
        }
    }

    // ---- epilogue: bias+relu into LDS f32[128][128], then coalesced fp16 stores
    __syncthreads();   // all waves finished reading staged operands from LDS
    float (*ldsF)[128] = (float (*)[128])(&lds[0][0]);
#pragma unroll
    for (int ni = 0; ni < 4; ni++) {
        int colL = wc * 64 + ni * 16 + (lane & 15);
        float bb = bias[col0 + colL];
#pragma unroll
        for (int mi = 0; mi < 4; mi++) {
#pragma unroll
            for (int j = 0; j < 4; j++) {
                int rowL = wr * 64 + mi * 16 + (lane >> 4) * 4 + j;
                ldsF[rowL][colL] = fmaxf(acc[mi][ni][j] + bb, 0.0f);
            }
        }
    }
    __syncthreads();
    int rL = tid >> 1;                 // 0..127 block-local row
    int cb = (tid & 1) * 8;            // interleaved 16B chunks within the row
    int lr = row0 + rL;
    if (lr < N_NODES) {
        size_t gb = (size_t)lr * H1 + col0;
#pragma unroll
        for (int c = 0; c < 8; c++) {
            int col = c * 16 + cb;     // 8 consecutive u16 = 16 B
            u16 hv[8];
#pragma unroll
            for (int e = 0; e < 8; e++)
                hv[e] = f16_bits((f16)ldsF[rL][col + e]);
            *(f16x8*)&Xf[gb + col] = *(f16x8*)hv;
        }
    }
}

// ---------------- GEMM2 via FP16 MFMA (A single fp16, B hi/lo fp16: 2 products) ----
// Single launch, 128x128 tile, BK=32, 4 waves; 3 staged tiles (24 KB LDS).
// XCD-aware remap keeps one A row-panel per XCD (grid NB=1256, %8==0).
__global__ __launch_bounds__(256) void gemm2_mfma(const u16* __restrict__ Af,
                                                  const u16* __restrict__ Bh,
                                                  const u16* __restrict__ Bl,
                                                  float* __restrict__ C) {
    __shared__ u16 ldsA[128 * 32], ldsBh[128 * 32], ldsBl[128 * 32];  // 8 KB each
    const int tid  = threadIdx.x;
    const int wid  = tid >> 6;
    const int lane = tid & 63;
    const int wr   = wid >> 1, wc = wid & 1;

    // ---- XCD-aware bijective remap ----
    int NB = (int)(gridDim.x * gridDim.y);   // 8 * 157 = 1256, % 8 == 0
    int b  = (int)(blockIdx.y * gridDim.x + blockIdx.x);
    int lin = (b & 7) * (NB >> 3) + (b >> 3);
    const int col0 = (lin & 7) * 128;
    const int row0 = (lin >> 3) * 128;

    // staging: wid0 -> A rows 0-63, wid1 -> A rows 64-127, wid2 -> Bh, wid3 -> Bl
    const u16* gbase;
    u16* mybase;
    int rbase, niter;
    if      (wid == 0) { gbase = Af; mybase = ldsA;          rbase = row0;      niter = 4; }
    else if (wid == 1) { gbase = Af; mybase = ldsA + 2048;   rbase = row0 + 64; niter = 4; }
    else if (wid == 2) { gbase = Bh; mybase = ldsBh;         rbase = col0;      niter = 8; }
    else               { gbase = Bl; mybase = ldsBl;         rbase = col0;      niter = 8; }
    const int r_l  = lane >> 2;        // 0..15
    const int ks_l = (lane & 3) * 8;   // 0,8,16,24  (lds dest byte = lane*16, linear)

    int rows[8];
#pragma unroll
    for (int i = 0; i < 8; i++) {
        int r = rbase + i * 16 + r_l;
        if (wid < 2 && r > N_NODES - 1) r = N_NODES - 1;
        rows[i] = r;
    }

    f32x4 acc[4][4] = {};

    for (int kt = 0; kt < H1 / 32; ++kt) {
        int k0 = kt * 32;
        __syncthreads();   // previous compute done before overwrite
        for (int i = 0; i < niter; i++) {
            const u16* g = gbase + (size_t)rows[i] * H1 + k0 + ks_l;
            __builtin_amdgcn_global_load_lds(
                (const __attribute__((address_space(1))) void*)g,
                (__attribute__((address_space(3))) void*)(mybase + i * 512),
                16, 0, 0);
        }
        __syncthreads();   // compiler drains vmcnt before barrier

        f16x8 af[4];
#pragma unroll
        for (int mi = 0; mi < 4; mi++) {
            int r   = wr * 64 + mi * 16 + (lane & 15);
            int off = r * 32 + (lane >> 4) * 8;
            af[mi] = *(const f16x8*)&ldsA[off];
        }
#pragma unroll
        for (int ni = 0; ni < 4; ni++) {
            int c   = wc * 64 + ni * 16 + (lane & 15);
            int off = c * 32 + (lane >> 4) * 8;
            f16x8 bfh = *(const f16x8*)&ldsBh[off];
            f16x8 bfl = *(const f16x8*)&ldsBl[off];
#pragma unroll
            for (int mi = 0; mi < 4; mi++) {
                acc[mi][ni] = __builtin_amdgcn_mfma_f32_16x16x32_f16(af[mi], bfh, acc[mi][ni], 0, 0, 0);
                acc[mi][ni] = __builtin_amdgcn_mfma_f32_16x16x32_f16(af[mi], bfl, acc[mi][ni], 0, 0, 0);
            }
        }
    }

    // C/D layout: col = lane&15, row = (lane>>4)*4 + j  [m89/m91 verified]
#pragma unroll
    for (int mi = 0; mi < 4; mi++) {
#pragma unroll
        for (int ni = 0; ni < 4; ni++) {
            int col = col0 + wc * 64 + ni * 16 + (lane & 15);
#pragma unroll
            for (int j = 0; j < 4; j++) {
                int lr = row0 + wr * 64 + mi * 16 + (lane >> 4) * 4 + j;
                if (lr < N_NODES) C[(size_t)lr * H2 + col] = acc[mi][ni][j];
            }
        }
    }
}

// ---------------- layer-2 aggregation via CSR gather (1024-dim), bias+relu fused ----
__global__ __launch_bounds__(256) void agg_csr_1024(const int* __restrict__ off,
                                                    const int* __restrict__ csr_src,
                                                    const float* __restrict__ csr_nrm,
                                                    const float* __restrict__ xw,
                                                    const float* __restrict__ b,
                                                    float* __restrict__ x2) {
    int node = blockIdx.x;
    int p0 = off[node], p1 = off[node + 1];
    int d = threadIdx.x;             // float4 lane: 256 x 4 = 1024 dims
    float4 a0 = make_float4(0.f, 0.f, 0.f, 0.f);
    float4 a1 = make_float4(0.f, 0.f, 0.f, 0.f);
    int p = p0;
    for (; p + 1 < p1; p += 2) {
        int   s0 = csr_src[p],     s1 = csr_src[p + 1];
        float n0 = csr_nrm[p],     n1 = csr_nrm[p + 1];
        float4 v0 = ((const float4*)&xw[(size_t)s0 * H2])[d];
        float4 v1 = ((const float4*)&xw[(size_t)s1 * H2])[d];
        a0.x += v0.x * n0; a0.y += v0.y * n0; a0.z += v0.z * n0; a0.w += v0.w * n0;
        a1.x += v1.x * n1; a1.y += v1.y * n1; a1.z += v1.z * n1; a1.w += v1.w * n1;
    }
    if (p < p1) {
        int   s0 = csr_src[p];
        float n0 = csr_nrm[p];
        float4 v0 = ((const float4*)&xw[(size_t)s0 * H2])[d];
        a0.x += v0.x * n0; a0.y += v0.y * n0; a0.z += v0.z * n0; a0.w += v0.w * n0;
    }
    float4 bb = ((const float4*)b)[d];
    float4 o;
    o.x = fmaxf(a0.x + a1.x + bb.x, 0.f);
    o.y = fmaxf(a0.y + a1.y + bb.y, 0.f);
    o.z = fmaxf(a0.z + a1.z + bb.z, 0.f);
    o.w = fmaxf(a0.w + a1.w + bb.w, 0.f);
    ((float4*)&x2[(size_t)node * H2])[d] = o;
}

// ---------------- pooling ----------------
__global__ void cnt_accum(const int* __restrict__ batch, float* cnt) {
    int i = blockIdx.x * 256 + threadIdx.x;
    if (i < N_NODES) atomicAdd(&cnt[batch[i]], 1.0f);
}

__global__ void pool_accum(const int* __restrict__ batch, const float* __restrict__ x2,
                           float* __restrict__ pooled) {
    int d  = blockIdx.x * 256 + threadIdx.x;   // 0..1023
    int i0 = blockIdx.y * 64;
    float acc = 0.0f;
    int gprev = -1;
    for (int i = 0; i < 64; i++) {
        int node = i0 + i;
        if (node >= N_NODES) break;
        int g = batch[node];
        if (g != gprev) {
            if (gprev >= 0) atomicAdd(&pooled[gprev * H2 + d], acc);
            acc = 0.0f; gprev = g;
        }
        acc += x2[(size_t)node * H2 + d];
    }
    if (gprev >= 0) atomicAdd(&pooled[gprev * H2 + d], acc);
}

__global__ void pool_norm(float* pooled, const float* cnt) {
    int idx = blockIdx.x * 256 + threadIdx.x;
    if (idx < N_GRAPHS * H2) {
        int g = idx >> 10;
        pooled[idx] /= fmaxf(cnt[g], 1.0f);
    }
}

// ---------------- MLP head (R6-proven k-split atomic version) ----------------
__global__ __launch_bounds__(256) void head_gemm(const float* __restrict__ In,
                                                 const float* __restrict__ W,
                                                 float* __restrict__ Out, int K, int N) {
    __shared__ __align__(16) float As[16][256];
    int n  = blockIdx.x * 256 + threadIdx.x;
    int m0 = blockIdx.y * 16;
    int k0 = blockIdx.z * 256;
    for (int t = threadIdx.x; t < 16 * 256; t += 256) {
        int r = t >> 8, k = t & 255;
        As[r][k] = In[(size_t)(m0 + r) * K + k0 + k];
    }
    __syncthreads();
    float acc[16] = {};
    for (int k = 0; k < 256; k += 4) {
        float w0 = W[(size_t)(k0 + k + 0) * N + n];
        float w1 = W[(size_t)(k0 + k + 1) * N + n];
        float w2 = W[(size_t)(k0 + k + 2) * N + n];
        float w3 = W[(size_t)(k0 + k + 3) * N + n];
#pragma unroll
        for (int r = 0; r < 16; r++) {
            float4 a = *(const float4*)&As[r][k];
            acc[r] += a.x * w0 + a.y * w1 + a.z * w2 + a.w * w3;
        }
    }
    for (int r = 0; r < 16; r++)
        atomicAdd(&Out[(size_t)(m0 + r) * N + n], acc[r]);
}

__global__ void bias_relu_MN(float* __restrict__ x, const float* __restrict__ b,
                             int N, int total) {
    int idx = blockIdx.x * 256 + threadIdx.x;
    if (idx < total) {
        int d = idx & (N - 1);    // N is a power of two
        x[idx] = fmaxf(x[idx] + b[d], 0.0f);
    }
}

__global__ void head3(const float* __restrict__ h2, const float* __restrict__ oW,
                      const float* __restrict__ ob, float* __restrict__ out) {
    int tid = threadIdx.x;          // 128 threads: m = tid/2, c = tid&1
    if (tid >= 128) return;
    int m = tid >> 1, c = tid & 1;
    float acc = 0.0f;
    for (int k = 0; k < 512; k++) acc += h2[m * 512 + k] * oW[k * 2 + c];
    out[tid] = acc + ob[c];
}

// ---------------- host ----------------
extern "C" void kernel_launch(void* const* d_in, const int* in_sizes, int n_in,
                              void* d_out, int out_size, void* d_ws, size_t ws_size,
                              hipStream_t stream) {
    const int*   ids   = (const int*)d_in[0];
    const float* other = (const float*)d_in[1];
    const int*   ei    = (const int*)d_in[2];
    const int*   batch = (const int*)d_in[3];
    const float* emb   = (const float*)d_in[4];
    const float* W1    = (const float*)d_in[5];
    const float* b1    = (const float*)d_in[6];
    const float* W2    = (const float*)d_in[7];
    const float* b2    = (const float*)d_in[8];
    const float* hW1   = (const float*)d_in[9];
    const float* hb1   = (const float*)d_in[10];
    const float* hW2   = (const float*)d_in[11];
    const float* hb2   = (const float*)d_in[12];
    const float* oW    = (const float*)d_in[13];
    const float* ob    = (const float*)d_in[14];
    float* out = (float*)d_out;

    char* ws = (char*)d_ws;
    size_t off_b = 0;
    auto alloc = [&](size_t bytes) {
        size_t p = (off_b + 255) & ~(size_t)255;
        off_b = p + bytes;
        return p;
    };
    // total ~182 MB (proven budget 254 MB)
    size_t o_dinv = alloc((size_t)N_NODES * 4);
    size_t o_indeg= alloc((size_t)(N_NODES + 1) * 4);
    size_t o_off  = alloc((size_t)(N_NODES + 1) * 4);
    size_t o_cur  = alloc((size_t)N_NODES * 4);
    size_t o_csrc = alloc((size_t)N_TOT_E * 4);
    size_t o_cnrm = alloc((size_t)N_TOT_E * 4);
    size_t o_xf   = alloc((size_t)N_NODES * IN_GNN * 4);
    size_t o_aggh = alloc((size_t)N_NODES * K1PAD * 2);  // bf16 hi, padded
    size_t o_aggl = alloc((size_t)N_NODES * K1PAD * 2);  // bf16 lo
    size_t o_w1h  = alloc((size_t)H1 * K1PAD * 2);       // W1^T hi bf16 [2048][64]
    size_t o_w1l  = alloc((size_t)H1 * K1PAD * 2);
    size_t o_x1f  = alloc((size_t)N_NODES * H1 * 2);     // x1 FP16 single, FULL size (82 MB)
    size_t o_w2h  = alloc((size_t)H2 * H1 * 2);          // W2^T hi fp16 [1024][2048]
    size_t o_w2l  = alloc((size_t)H2 * H1 * 2);
    size_t o_xw2  = alloc((size_t)N_NODES * H2 * 4);
    size_t o_pool = alloc((size_t)N_GRAPHS * H2 * 4);
    size_t o_cnt  = alloc((size_t)N_GRAPHS * 4);
    size_t o_h1   = alloc((size_t)N_GRAPHS * 1024 * 4);
    size_t o_h2   = alloc((size_t)N_GRAPHS * 512 * 4);

    float* dinv = (float*)(ws + o_dinv);
    int*   indeg= (int*)(ws + o_indeg);
    int*   offs = (int*)(ws + o_off);
    int*   cur  = (int*)(ws + o_cur);
    int*   csrc = (int*)(ws + o_csrc);
    float* cnrm = (float*)(ws + o_cnrm);
    float* xf   = (float*)(ws + o_xf);
    u16*   aggh = (u16*)(ws + o_aggh);
    u16*   aggl = (u16*)(ws + o_aggl);
    u16*   w1h  = (u16*)(ws + o_w1h);
    u16*   w1l  = (u16*)(ws + o_w1l);
    u16*   x1f  = (u16*)(ws + o_x1f);
    u16*   w2h  = (u16*)(ws + o_w2h);
    u16*   w2l  = (u16*)(ws + o_w2l);
    float* xw2  = (float*)(ws + o_xw2);
    // x2 aliases x1f (81.92 MB == 80+ MB needed; x1f dead after gemm2)
    float* x2   = (float*)(ws + o_x1f);
    float* pooled = (float*)(ws + o_pool);
    float* cnt  = (float*)(ws + o_cnt);
    float* h1   = (float*)(ws + o_h1);
    float* h2   = (float*)(ws + o_h2);

    // indegree (int); self loop = init 1; dinv = rsqrt(deg)
    fill_i32<<<(N_NODES + 255) / 256, 256, 0, stream>>>(indeg, 1, N_NODES);
    deg_accum<<<(N_EDGES + 255) / 256, 256, 0, stream>>>(ei, indeg);
    deg_to_dinv<<<(N_NODES + 255) / 256, 256, 0, stream>>>(indeg, dinv);

    // CSR
    scan_offsets<<<1, 1024, 0, stream>>>(indeg, offs, cur);
    csr_fill<<<(N_TOT_E + 255) / 256, 256, 0, stream>>>(ei, dinv, cur, csrc, cnrm);

    // node features + layer-1 aggregation (full graph) -> padded hi/lo bf16
    build_xfeat<<<(N_NODES * IN_GNN + 255) / 256, 256, 0, stream>>>(ids, other, emb, xf);
    agg_csr_36<<<(N_NODES * K1PAD + 255) / 256, 256, 0, stream>>>(offs, csrc, cnrm, xf, aggh, aggl);

    // weights -> transposed splits (once)
    conv_w1<<<(H1 * K1PAD + 255) / 256, 256, 0, stream>>>(W1, w1h, w1l);
    conv_w2<<<dim3(H1 / 32, H2 / 32), 256, 0, stream>>>(W2, w2h, w2l);

    // layer 1 GEMM (single launch, all nodes) -> x1 fp16
    gemm1_mfma<<<dim3(H1 / 128, NPANELS), 256, 0, stream>>>(aggh, aggl, w1h, w1l, b1, x1f);

    // layer 2 GEMM (single launch; grid 8 x 157 = 1256, % 8 == 0)
    gemm2_mfma<<<dim3(H2 / 128, NPANELS), 256, 0, stream>>>(x1f, w2h, w2l, xw2);

    // layer-2 aggregation with bias+relu fused (x2 overwrites dead x1f region)
    agg_csr_1024<<<N_NODES, 256, 0, stream>>>(offs, csrc, cnrm, xw2, b2, x2);

    // mean pool
    hipMemsetAsync(pooled, 0, (size_t)N_GRAPHS * H2 * 4, stream);
    hipMemsetAsync(cnt, 0, (size_t)N_GRAPHS * 4, stream);
    cnt_accum<<<(N_NODES + 255) / 256, 256, 0, stream>>>(batch, cnt);
    pool_accum<<<dim3(H2 / 256, (N_NODES + 63) / 64), 256, 0, stream>>>(batch, x2, pooled);
    pool_norm<<<(N_GRAPHS * H2 + 255) / 256, 256, 0, stream>>>(pooled, cnt);

    // head (R6-proven)
    hipMemsetAsync(h1, 0, (size_t)N_GRAPHS * 1024 * 4, stream);
    head_gemm<<<dim3(1024 / 256, 4, 1024 / 256), 256, 0, stream>>>(pooled, hW1, h1, 1024, 1024);
    bias_relu_MN<<<(N_GRAPHS * 1024 + 255) / 256, 256, 0, stream>>>(h1, hb1, 1024, N_GRAPHS * 1024);

    hipMemsetAsync(h2, 0, (size_t)N_GRAPHS * 512 * 4, stream);
    head_gemm<<<dim3(512 / 256, 4, 1024 / 256), 256, 0, stream>>>(h1, hW2, h2, 1024, 512);
    bias_relu_MN<<<(N_GRAPHS * 512 + 255) / 256, 256, 0, stream>>>(h2, hb2, 512, N_GRAPHS * 512);

    head3<<<1, 128, 0, stream>>>(h2, oW, ob, out);
}

// Round 14
// 751.329 us; speedup vs baseline: 1.6629x; 1.1171x over previous
//
#include <hip/hip_runtime.h>
#include <hip/hip_bf16.h>

#define N_NODES  20000
#define N_EDGES  160000
#define N_TOT_E  180000   // edges + self loops
#define N_GRAPHS 64
#define EMBED_DIM 32
#define IN_GNN   36
#define K1PAD    64       // gemm1 K padded for MFMA
#define H1       2048
#define H2       1024
#define NPANELS  157      // ceil(20000/128)

typedef unsigned short u16;
typedef short bf16x8 __attribute__((ext_vector_type(8)));
typedef float f32x4  __attribute__((ext_vector_type(4)));
typedef _Float16 f16;
typedef f16  f16x8  __attribute__((ext_vector_type(8)));

__device__ inline u16 f32_to_bf16(float f) {
    union { float f; unsigned u; } v; v.f = f;
    unsigned lsb = (v.u >> 16) & 1u;
    return (u16)((v.u + 0x7fffu + lsb) >> 16);
}
__device__ inline float bf16_to_f32(u16 h) {
    union { unsigned u; float f; } v; v.u = ((unsigned)h) << 16;
    return v.f;
}
__device__ inline u16 f16_bits(f16 h) { union { f16 h; u16 u; } v; v.h = h; return v.u; }
__device__ inline float f16u_to_f32(u16 u) { union { u16 u; f16 h; } v; v.u = u; return (float)v.h; }

// ---------------- small utility kernels ----------------

__global__ void fill_i32(int* p, int v, int n) {
    int i = blockIdx.x * 256 + threadIdx.x;
    if (i < n) p[i] = v;
}

__global__ void deg_accum(const int* __restrict__ ei, int* indeg) {
    int e = blockIdx.x * 256 + threadIdx.x;
    if (e < N_EDGES) atomicAdd(&indeg[ei[N_EDGES + e]], 1);
}

__global__ void deg_to_dinv(const int* __restrict__ indeg, float* __restrict__ d) {
    int i = blockIdx.x * 256 + threadIdx.x;
    if (i < N_NODES) d[i] = rsqrtf((float)indeg[i]);   // deg >= 1 (self loop)
}

__global__ void build_xfeat(const int* __restrict__ ids, const float* __restrict__ other,
                            const float* __restrict__ emb, float* __restrict__ xf) {
    int idx = blockIdx.x * 256 + threadIdx.x;   // node*36 + d
    if (idx >= N_NODES * IN_GNN) return;
    int i = idx / IN_GNN;
    int d = idx - i * IN_GNN;
    float v = (d < EMBED_DIM) ? emb[(size_t)ids[i] * EMBED_DIM + d]
                              : other[i * 4 + (d - EMBED_DIM)];
    xf[idx] = v;
}

// ---------------- CSR build (R6-proven barrier scan) ----------------
__global__ __launch_bounds__(1024) void scan_offsets(const int* __restrict__ indeg,
                                                     int* __restrict__ off,
                                                     int* __restrict__ cursor) {
    __shared__ int buf[1024];
    __shared__ int base_s;
    int tid = threadIdx.x;
    if (tid == 0) base_s = 0;
    __syncthreads();
    for (int start = 0; start < N_NODES; start += 1024) {
        int i = start + tid;
        int v = (i < N_NODES) ? indeg[i] : 0;
        buf[tid] = v;
        __syncthreads();
        for (int s = 1; s < 1024; s <<= 1) {
            int t = (tid >= s) ? buf[tid - s] : 0;
            __syncthreads();
            buf[tid] += t;
            __syncthreads();
        }
        int incl = buf[tid];
        int excl = incl - v;
        int base = base_s;
        if (i < N_NODES) {
            int o = base + excl;
            off[i] = o;
            cursor[i] = o;
        }
        __syncthreads();
        if (tid == 1023) base_s = base + incl;
        __syncthreads();
    }
    if (tid == 0) off[N_NODES] = N_TOT_E;
}

__global__ void csr_fill(const int* __restrict__ ei, const float* __restrict__ dinv,
                         int* __restrict__ cursor,
                         int* __restrict__ csr_src, float* __restrict__ csr_nrm) {
    int e = blockIdx.x * 256 + threadIdx.x;
    if (e >= N_TOT_E) return;
    int s, t;
    if (e < N_EDGES) { s = ei[e]; t = ei[N_EDGES + e]; }
    else             { s = t = e - N_EDGES; }
    int pos = atomicAdd(&cursor[t], 1);
    csr_src[pos] = s;
    csr_nrm[pos] = dinv[s] * dinv[t];
}

// ---------------- layer-1 aggregation via CSR gather -> hi/lo bf16, [node][64] padded
__global__ void agg_csr_36(const int* __restrict__ off, const int* __restrict__ csr_src,
                           const float* __restrict__ csr_nrm,
                           const float* __restrict__ xf,
                           u16* __restrict__ aggh, u16* __restrict__ aggl) {
    int idx = blockIdx.x * 256 + threadIdx.x;   // node*64 + d
    if (idx >= N_NODES * K1PAD) return;
    int node = idx >> 6;
    int d = idx & 63;
    u16 hi = 0, lo = 0;
    if (d < IN_GNN) {
        int p0 = off[node], p1 = off[node + 1];
        float acc = 0.0f;
        for (int p = p0; p < p1; p++)
            acc += xf[csr_src[p] * IN_GNN + d] * csr_nrm[p];
        hi = f32_to_bf16(acc);
        lo = f32_to_bf16(acc - bf16_to_f32(hi));
    }
    aggh[idx] = hi;
    aggl[idx] = lo;
}

// ---------------- W1 [36,2048] f32 -> transposed hi/lo bf16 [2048][64] (padded) ----
__global__ void conv_w1(const float* __restrict__ W,
                        u16* __restrict__ Bh, u16* __restrict__ Bl) {
    int idx = blockIdx.x * 256 + threadIdx.x;   // n*64 + k
    if (idx >= H1 * K1PAD) return;
    int n = idx >> 6;
    int k = idx & 63;
    u16 hi = 0, lo = 0;
    if (k < IN_GNN) {
        float v = W[(size_t)k * H1 + n];
        hi = f32_to_bf16(v);
        lo = f32_to_bf16(v - bf16_to_f32(hi));
    }
    Bh[idx] = hi;
    Bl[idx] = lo;
}

// ---------------- W2 [2048,1024] f32 -> transposed hi/lo FP16 [1024,2048] ----------
__global__ __launch_bounds__(256) void conv_w2(const float* __restrict__ W,
                                               u16* __restrict__ Bh,
                                               u16* __restrict__ Bl) {
    __shared__ float t[32][33];
    int bk = blockIdx.x * 32;   // k block
    int bn = blockIdx.y * 32;   // n block
    int tx = threadIdx.x & 31, ty = threadIdx.x >> 5;   // 32 x 8
#pragma unroll
    for (int i = 0; i < 32; i += 8)
        t[ty + i][tx] = W[(size_t)(bk + ty + i) * H2 + bn + tx];
    __syncthreads();
#pragma unroll
    for (int i = 0; i < 32; i += 8) {
        float v = t[tx][ty + i];            // = W[bk+tx][bn+ty+i]
        f16 h = (f16)v;
        f16 l = (f16)(v - (float)h);
        size_t o = (size_t)(bn + ty + i) * H1 + bk + tx;   // Bt[n][k]
        Bh[o] = f16_bits(h);
        Bl[o] = f16_bits(l);
    }
}

// ---------------- GEMM1 via bf16 MFMA: agg[rows,64p] @ W1t[2048,64p] + b1, relu ----
// Single launch over all nodes. Epilogue: LDS-staged f32, then single FP16 output
// (x1f) via coalesced 16B stores.
__global__ __launch_bounds__(256) void gemm1_mfma(const u16* __restrict__ Ah,
                                                  const u16* __restrict__ Al,
                                                  const u16* __restrict__ Bh,
                                                  const u16* __restrict__ Bl,
                                                  const float* __restrict__ bias,
                                                  u16* __restrict__ Xf) {
    __shared__ __align__(16) u16 lds[4][128 * K1PAD];   // 16 KB each, 64 KB total
    const int tid  = threadIdx.x;
    const int wid  = tid >> 6;
    const int lane = tid & 63;
    const int wr   = wid >> 1, wc = wid & 1;
    const int row0 = blockIdx.y * 128;          // global rows
    const int col0 = blockIdx.x * 128;          // over H1=2048

    const u16* gbase;
    int rbase; bool isA;
    if      (wid == 0) { gbase = Ah; rbase = row0; isA = true; }
    else if (wid == 1) { gbase = Al; rbase = row0; isA = true; }
    else if (wid == 2) { gbase = Bh; rbase = col0; isA = false; }
    else               { gbase = Bl; rbase = col0; isA = false; }
    u16* myl = lds[wid];
    const int r_l  = lane >> 3;        // 0..7 row within 8-row group
    const int ks_l = (lane & 7) * 8;   // k offset
#pragma unroll
    for (int i = 0; i < 16; i++) {
        int r = rbase + i * 8 + r_l;
        if (isA && r > N_NODES - 1) r = N_NODES - 1;
        const u16* g = gbase + (size_t)r * K1PAD + ks_l;
        __builtin_amdgcn_global_load_lds(
            (const __attribute__((address_space(1))) void*)g,
            (__attribute__((address_space(3))) void*)(myl + i * 512),
            16, 0, 0);
    }
    __syncthreads();   // drains vmcnt; all 4 tiles visible

    f32x4 acc[4][4] = {};
#pragma unroll
    for (int ks = 0; ks < 2; ks++) {
        bf16x8 afh[4], afl[4];
#pragma unroll
        for (int mi = 0; mi < 4; mi++) {
            int r   = wr * 64 + mi * 16 + (lane & 15);
            int off = r * K1PAD + ks * 32 + (lane >> 4) * 8;
            afh[mi] = *(const bf16x8*)&lds[0][off];
            afl[mi] = *(const bf16x8*)&lds[1][off];
        }
#pragma unroll
        for (int ni = 0; ni < 4; ni++) {
            int c   = wc * 64 + ni * 16 + (lane & 15);
            int off = c * K1PAD + ks * 32 + (lane >> 4) * 8;
            bf16x8 bfh = *(const bf16x8*)&lds[2][off];
            bf16x8 bfl = *(const bf16x8*)&lds[3][off];
#pragma unroll
            for (int mi = 0; mi < 4; mi++) {
                acc[mi][ni] = __builtin_amdgcn_mfma_f32_16x16x32_bf16(afh[mi], bfh, acc[mi][ni], 0, 0, 0);
                acc[mi][ni] = __builtin_amdgcn_mfma_f32_16x16x32_bf16(afh[mi], bfl, acc[mi][ni], 0, 0, 0);
                acc[mi][ni] = __builtin_amdgcn_mfma_f32_16x16x32_bf16(afl[mi], bfh, acc[mi][ni], 0, 0, 0);
            }
        }
    }

    // ---- epilogue: bias+relu into LDS f32[128][128], then coalesced fp16 stores
    __syncthreads();   // all waves finished reading staged operands from LDS
    float (*ldsF)[128] = (float (*)[128])(&lds[0][0]);
#pragma unroll
    for (int ni = 0; ni < 4; ni++) {
        int colL = wc * 64 + ni * 16 + (lane & 15);
        float bb = bias[col0 + colL];
#pragma unroll
        for (int mi = 0; mi < 4; mi++) {
#pragma unroll
            for (int j = 0; j < 4; j++) {
                int rowL = wr * 64 + mi * 16 + (lane >> 4) * 4 + j;
                ldsF[rowL][colL] = fmaxf(acc[mi][ni][j] + bb, 0.0f);
            }
        }
    }
    __syncthreads();
    int rL = tid >> 1;                 // 0..127 block-local row
    int cb = (tid & 1) * 8;            // interleaved 16B chunks within the row
    int lr = row0 + rL;
    if (lr < N_NODES) {
        size_t gb = (size_t)lr * H1 + col0;
#pragma unroll
        for (int c = 0; c < 8; c++) {
            int col = c * 16 + cb;     // 8 consecutive u16 = 16 B
            u16 hv[8];
#pragma unroll
            for (int e = 0; e < 8; e++)
                hv[e] = f16_bits((f16)ldsF[rL][col + e]);
            *(f16x8*)&Xf[gb + col] = *(f16x8*)hv;
        }
    }
}

// ---------------- GEMM2 via FP16 MFMA (A single fp16, B hi/lo fp16: 2 products) ----
// BK=64 per barrier phase (two BK=32 sub-tiles staged together): 6 x 8KB = 48 KB LDS,
// 64 MFMA per phase, 32 phases. Output fp16. XCD remap (grid 1256, %8==0).
__global__ __launch_bounds__(256) void gemm2_mfma(const u16* __restrict__ Af,
                                                  const u16* __restrict__ Bh,
                                                  const u16* __restrict__ Bl,
                                                  u16* __restrict__ C) {
    // tile index: 0=A_s0 1=A_s1 2=Bh_s0 3=Bh_s1 4=Bl_s0 5=Bl_s1  (each [128][32] u16)
    __shared__ u16 lds[6][128 * 32];
    const int tid  = threadIdx.x;
    const int wid  = tid >> 6;
    const int lane = tid & 63;
    const int wr   = wid >> 1, wc = wid & 1;

    // ---- XCD-aware bijective remap ----
    int NB = (int)(gridDim.x * gridDim.y);   // 8 * 157 = 1256, % 8 == 0
    int b  = (int)(blockIdx.y * gridDim.x + blockIdx.x);
    int lin = (b & 7) * (NB >> 3) + (b >> 3);
    const int col0 = (lin & 7) * 128;
    const int row0 = (lin >> 3) * 128;

    const int r_l  = lane >> 2;        // 0..15 row within 16-row unit
    const int ks_l = (lane & 3) * 8;   // u16 k-offset within 32-k sub-tile

    f32x4 acc[4][4] = {};

    for (int kt = 0; kt < H1 / 64; ++kt) {        // 32 phases
        int k0 = kt * 64;
        __syncthreads();   // previous compute done before overwrite
        // 48 staging units (64 lanes x 16B each); wave wid does units wid*12..+11
        for (int u = wid * 12; u < wid * 12 + 12; u++) {
            int tile = u >> 3;          // 0..5
            int it   = u & 7;           // 16-row unit within tile
            int s    = tile & 1;        // k sub-step
            int t    = tile >> 1;       // 0=A 1=Bh 2=Bl
            const u16* g = (t == 0) ? Af : (t == 1) ? Bh : Bl;
            int r = ((t == 0) ? row0 : col0) + it * 16 + r_l;
            if (t == 0 && r > N_NODES - 1) r = N_NODES - 1;
            const u16* src = g + (size_t)r * H1 + k0 + s * 32 + ks_l;
            __builtin_amdgcn_global_load_lds(
                (const __attribute__((address_space(1))) void*)src,
                (__attribute__((address_space(3))) void*)(&lds[tile][it * 512]),
                16, 0, 0);
        }
        __syncthreads();   // compiler drains vmcnt before barrier

#pragma unroll
        for (int ks = 0; ks < 2; ks++) {
            f16x8 af[4];
#pragma unroll
            for (int mi = 0; mi < 4; mi++) {
                int r   = wr * 64 + mi * 16 + (lane & 15);
                int off = r * 32 + (lane >> 4) * 8;
                af[mi] = *(const f16x8*)&lds[ks][off];
            }
#pragma unroll
            for (int ni = 0; ni < 4; ni++) {
                int c   = wc * 64 + ni * 16 + (lane & 15);
                int off = c * 32 + (lane >> 4) * 8;
                f16x8 bfh = *(const f16x8*)&lds[2 + ks][off];
                f16x8 bfl = *(const f16x8*)&lds[4 + ks][off];
#pragma unroll
                for (int mi = 0; mi < 4; mi++) {
                    acc[mi][ni] = __builtin_amdgcn_mfma_f32_16x16x32_f16(af[mi], bfh, acc[mi][ni], 0, 0, 0);
                    acc[mi][ni] = __builtin_amdgcn_mfma_f32_16x16x32_f16(af[mi], bfl, acc[mi][ni], 0, 0, 0);
                }
            }
        }
    }

    // C/D layout: col = lane&15, row = (lane>>4)*4 + j  [m89/m91 verified]; fp16 out
#pragma unroll
    for (int mi = 0; mi < 4; mi++) {
#pragma unroll
        for (int ni = 0; ni < 4; ni++) {
            int col = col0 + wc * 64 + ni * 16 + (lane & 15);
#pragma unroll
            for (int j = 0; j < 4; j++) {
                int lr = row0 + wr * 64 + mi * 16 + (lane >> 4) * 4 + j;
                if (lr < N_NODES) C[(size_t)lr * H2 + col] = f16_bits((f16)acc[mi][ni][j]);
            }
        }
    }
}

// ---------------- layer-2 aggregation via CSR gather (fp16 in, f32 out) ------------
__global__ __launch_bounds__(256) void agg_csr_1024(const int* __restrict__ off,
                                                    const int* __restrict__ csr_src,
                                                    const float* __restrict__ csr_nrm,
                                                    const u16* __restrict__ xw,
                                                    const float* __restrict__ b,
                                                    float* __restrict__ x2) {
    int node = blockIdx.x;
    int p0 = off[node], p1 = off[node + 1];
    int d = threadIdx.x;             // 4 dims per thread: d*4 .. d*4+3
    float4 a0 = make_float4(0.f, 0.f, 0.f, 0.f);
    float4 a1 = make_float4(0.f, 0.f, 0.f, 0.f);
    int p = p0;
    for (; p + 1 < p1; p += 2) {
        int   s0 = csr_src[p],     s1 = csr_src[p + 1];
        float n0 = csr_nrm[p],     n1 = csr_nrm[p + 1];
        ushort4 v0 = ((const ushort4*)&xw[(size_t)s0 * H2])[d];
        ushort4 v1 = ((const ushort4*)&xw[(size_t)s1 * H2])[d];
        a0.x += f16u_to_f32(v0.x) * n0; a0.y += f16u_to_f32(v0.y) * n0;
        a0.z += f16u_to_f32(v0.z) * n0; a0.w += f16u_to_f32(v0.w) * n0;
        a1.x += f16u_to_f32(v1.x) * n1; a1.y += f16u_to_f32(v1.y) * n1;
        a1.z += f16u_to_f32(v1.z) * n1; a1.w += f16u_to_f32(v1.w) * n1;
    }
    if (p < p1) {
        int   s0 = csr_src[p];
        float n0 = csr_nrm[p];
        ushort4 v0 = ((const ushort4*)&xw[(size_t)s0 * H2])[d];
        a0.x += f16u_to_f32(v0.x) * n0; a0.y += f16u_to_f32(v0.y) * n0;
        a0.z += f16u_to_f32(v0.z) * n0; a0.w += f16u_to_f32(v0.w) * n0;
    }
    float4 bb = ((const float4*)b)[d];
    float4 o;
    o.x = fmaxf(a0.x + a1.x + bb.x, 0.f);
    o.y = fmaxf(a0.y + a1.y + bb.y, 0.f);
    o.z = fmaxf(a0.z + a1.z + bb.z, 0.f);
    o.w = fmaxf(a0.w + a1.w + bb.w, 0.f);
    ((float4*)&x2[(size_t)node * H2])[d] = o;
}

// ---------------- pooling ----------------
__global__ void cnt_accum(const int* __restrict__ batch, float* cnt) {
    int i = blockIdx.x * 256 + threadIdx.x;
    if (i < N_NODES) atomicAdd(&cnt[batch[i]], 1.0f);
}

__global__ void pool_accum(const int* __restrict__ batch, const float* __restrict__ x2,
                           float* __restrict__ pooled) {
    int d  = blockIdx.x * 256 + threadIdx.x;   // 0..1023
    int i0 = blockIdx.y * 64;
    float acc = 0.0f;
    int gprev = -1;
    for (int i = 0; i < 64; i++) {
        int node = i0 + i;
        if (node >= N_NODES) break;
        int g = batch[node];
        if (g != gprev) {
            if (gprev >= 0) atomicAdd(&pooled[gprev * H2 + d], acc);
            acc = 0.0f; gprev = g;
        }
        acc += x2[(size_t)node * H2 + d];
    }
    if (gprev >= 0) atomicAdd(&pooled[gprev * H2 + d], acc);
}

__global__ void pool_norm(float* pooled, const float* cnt) {
    int idx = blockIdx.x * 256 + threadIdx.x;
    if (idx < N_GRAPHS * H2) {
        int g = idx >> 10;
        pooled[idx] /= fmaxf(cnt[g], 1.0f);
    }
}

// ---------------- MLP head (R6-proven k-split atomic version) ----------------
__global__ __launch_bounds__(256) void head_gemm(const float* __restrict__ In,
                                                 const float* __restrict__ W,
                                                 float* __restrict__ Out, int K, int N) {
    __shared__ __align__(16) float As[16][256];
    int n  = blockIdx.x * 256 + threadIdx.x;
    int m0 = blockIdx.y * 16;
    int k0 = blockIdx.z * 256;
    for (int t = threadIdx.x; t < 16 * 256; t += 256) {
        int r = t >> 8, k = t & 255;
        As[r][k] = In[(size_t)(m0 + r) * K + k0 + k];
    }
    __syncthreads();
    float acc[16] = {};
    for (int k = 0; k < 256; k += 4) {
        float w0 = W[(size_t)(k0 + k + 0) * N + n];
        float w1 = W[(size_t)(k0 + k + 1) * N + n];
        float w2 = W[(size_t)(k0 + k + 2) * N + n];
        float w3 = W[(size_t)(k0 + k + 3) * N + n];
#pragma unroll
        for (int r = 0; r < 16; r++) {
            float4 a = *(const float4*)&As[r][k];
            acc[r] += a.x * w0 + a.y * w1 + a.z * w2 + a.w * w3;
        }
    }
    for (int r = 0; r < 16; r++)
        atomicAdd(&Out[(size_t)(m0 + r) * N + n], acc[r]);
}

__global__ void bias_relu_MN(float* __restrict__ x, const float* __restrict__ b,
                             int N, int total) {
    int idx = blockIdx.x * 256 + threadIdx.x;
    if (idx < total) {
        int d = idx & (N - 1);    // N is a power of two
        x[idx] = fmaxf(x[idx] + b[d], 0.0f);
    }
}

__global__ void head3(const float* __restrict__ h2, const float* __restrict__ oW,
                      const float* __restrict__ ob, float* __restrict__ out) {
    int tid = threadIdx.x;          // 128 threads: m = tid/2, c = tid&1
    if (tid >= 128) return;
    int m = tid >> 1, c = tid & 1;
    float acc = 0.0f;
    for (int k = 0; k < 512; k++) acc += h2[m * 512 + k] * oW[k * 2 + c];
    out[tid] = acc + ob[c];
}

// ---------------- host ----------------
extern "C" void kernel_launch(void* const* d_in, const int* in_sizes, int n_in,
                              void* d_out, int out_size, void* d_ws, size_t ws_size,
                              hipStream_t stream) {
    const int*   ids   = (const int*)d_in[0];
    const float* other = (const float*)d_in[1];
    const int*   ei    = (const int*)d_in[2];
    const int*   batch = (const int*)d_in[3];
    const float* emb   = (const float*)d_in[4];
    const float* W1    = (const float*)d_in[5];
    const float* b1    = (const float*)d_in[6];
    const float* W2    = (const float*)d_in[7];
    const float* b2    = (const float*)d_in[8];
    const float* hW1   = (const float*)d_in[9];
    const float* hb1   = (const float*)d_in[10];
    const float* hW2   = (const float*)d_in[11];
    const float* hb2   = (const float*)d_in[12];
    const float* oW    = (const float*)d_in[13];
    const float* ob    = (const float*)d_in[14];
    float* out = (float*)d_out;

    char* ws = (char*)d_ws;
    size_t off_b = 0;
    auto alloc = [&](size_t bytes) {
        size_t p = (off_b + 255) & ~(size_t)255;
        off_b = p + bytes;
        return p;
    };
    // total ~142 MB (proven budget 254 MB)
    size_t o_dinv = alloc((size_t)N_NODES * 4);
    size_t o_indeg= alloc((size_t)(N_NODES + 1) * 4);
    size_t o_off  = alloc((size_t)(N_NODES + 1) * 4);
    size_t o_cur  = alloc((size_t)N_NODES * 4);
    size_t o_csrc = alloc((size_t)N_TOT_E * 4);
    size_t o_cnrm = alloc((size_t)N_TOT_E * 4);
    size_t o_xf   = alloc((size_t)N_NODES * IN_GNN * 4);
    size_t o_aggh = alloc((size_t)N_NODES * K1PAD * 2);  // bf16 hi, padded
    size_t o_aggl = alloc((size_t)N_NODES * K1PAD * 2);  // bf16 lo
    size_t o_w1h  = alloc((size_t)H1 * K1PAD * 2);       // W1^T hi bf16 [2048][64]
    size_t o_w1l  = alloc((size_t)H1 * K1PAD * 2);
    size_t o_x1f  = alloc((size_t)N_NODES * H1 * 2);     // x1 FP16 single (82 MB)
    size_t o_w2h  = alloc((size_t)H2 * H1 * 2);          // W2^T hi fp16 [1024][2048]
    size_t o_w2l  = alloc((size_t)H2 * H1 * 2);
    size_t o_xw2  = alloc((size_t)N_NODES * H2 * 2);     // xw2 FP16 (41 MB)
    size_t o_pool = alloc((size_t)N_GRAPHS * H2 * 4);
    size_t o_cnt  = alloc((size_t)N_GRAPHS * 4);
    size_t o_h1   = alloc((size_t)N_GRAPHS * 1024 * 4);
    size_t o_h2   = alloc((size_t)N_GRAPHS * 512 * 4);

    float* dinv = (float*)(ws + o_dinv);
    int*   indeg= (int*)(ws + o_indeg);
    int*   offs = (int*)(ws + o_off);
    int*   cur  = (int*)(ws + o_cur);
    int*   csrc = (int*)(ws + o_csrc);
    float* cnrm = (float*)(ws + o_cnrm);
    float* xf   = (float*)(ws + o_xf);
    u16*   aggh = (u16*)(ws + o_aggh);
    u16*   aggl = (u16*)(ws + o_aggl);
    u16*   w1h  = (u16*)(ws + o_w1h);
    u16*   w1l  = (u16*)(ws + o_w1l);
    u16*   x1f  = (u16*)(ws + o_x1f);
    u16*   w2h  = (u16*)(ws + o_w2h);
    u16*   w2l  = (u16*)(ws + o_w2l);
    u16*   xw2  = (u16*)(ws + o_xw2);
    // x2 (f32, 80 MB) aliases x1f (81.92 MB; dead after gemm2)
    float* x2   = (float*)(ws + o_x1f);
    float* pooled = (float*)(ws + o_pool);
    float* cnt  = (float*)(ws + o_cnt);
    float* h1   = (float*)(ws + o_h1);
    float* h2   = (float*)(ws + o_h2);

    // indegree (int); self loop = init 1; dinv = rsqrt(deg)
    fill_i32<<<(N_NODES + 255) / 256, 256, 0, stream>>>(indeg, 1, N_NODES);
    deg_accum<<<(N_EDGES + 255) / 256, 256, 0, stream>>>(ei, indeg);
    deg_to_dinv<<<(N_NODES + 255) / 256, 256, 0, stream>>>(indeg, dinv);

    // CSR
    scan_offsets<<<1, 1024, 0, stream>>>(indeg, offs, cur);
    csr_fill<<<(N_TOT_E + 255) / 256, 256, 0, stream>>>(ei, dinv, cur, csrc, cnrm);

    // node features + layer-1 aggregation (full graph) -> padded hi/lo bf16
    build_xfeat<<<(N_NODES * IN_GNN + 255) / 256, 256, 0, stream>>>(ids, other, emb, xf);
    agg_csr_36<<<(N_NODES * K1PAD + 255) / 256, 256, 0, stream>>>(offs, csrc, cnrm, xf, aggh, aggl);

    // weights -> transposed splits (once)
    conv_w1<<<(H1 * K1PAD + 255) / 256, 256, 0, stream>>>(W1, w1h, w1l);
    conv_w2<<<dim3(H1 / 32, H2 / 32), 256, 0, stream>>>(W2, w2h, w2l);

    // layer 1 GEMM (single launch, all nodes) -> x1 fp16
    gemm1_mfma<<<dim3(H1 / 128, NPANELS), 256, 0, stream>>>(aggh, aggl, w1h, w1l, b1, x1f);

    // layer 2 GEMM (single launch; grid 8 x 157 = 1256, % 8 == 0) -> xw2 fp16
    gemm2_mfma<<<dim3(H2 / 128, NPANELS), 256, 0, stream>>>(x1f, w2h, w2l, xw2);

    // layer-2 aggregation with bias+relu fused (x2 overwrites dead x1f region)
    agg_csr_1024<<<N_NODES, 256, 0, stream>>>(offs, csrc, cnrm, xw2, b2, x2);

    // mean pool
    hipMemsetAsync(pooled, 0, (size_t)N_GRAPHS * H2 * 4, stream);
    hipMemsetAsync(cnt, 0, (size_t)N_GRAPHS * 4, stream);
    cnt_accum<<<(N_NODES + 255) / 256, 256, 0, stream>>>(batch, cnt);
    pool_accum<<<dim3(H2 / 256, (N_NODES + 63) / 64), 256, 0, stream>>>(batch, x2, pooled);
    pool_norm<<<(N_GRAPHS * H2 + 255) / 256, 256, 0, stream>>>(pooled, cnt);

    // head (R6-proven)
    hipMemsetAsync(h1, 0, (size_t)N_GRAPHS * 1024 * 4, stream);
    head_gemm<<<dim3(1024 / 256, 4, 1024 / 256), 256, 0, stream>>>(pooled, hW1, h1, 1024, 1024);
    bias_relu_MN<<<(N_GRAPHS * 1024 + 255) / 256, 256, 0, stream>>>(h1, hb1, 1024, N_GRAPHS * 1024);

    hipMemsetAsync(h2, 0, (size_t)N_GRAPHS * 512 * 4, stream);
    head_gemm<<<dim3(512 / 256, 4, 1024 / 256), 256, 0, stream>>>(h1, hW2, h2, 1024, 512);
    bias_relu_MN<<<(N_GRAPHS * 512 + 255) / 256, 256, 0, stream>>>(h2, hb2, 512, N_GRAPHS * 512);

    head3<<<1, 128, 0, stream>>>(h2, oW, ob, out);
}